// Round 13
// baseline (1099.676 us; speedup 1.0000x reference)
//
#include <hip/hip_runtime.h>
#include <math.h>

#define DEV static __device__ __forceinline__

typedef __attribute__((ext_vector_type(8))) short bf16x8;
typedef __attribute__((ext_vector_type(4))) float f32x4;

DEV float gelu_exact(float x) {
    return 0.5f * x * (1.0f + erff(x * 0.70710678118654752f));
}

DEV short f2bf(float f) {
    union { float f; unsigned u; } v; v.f = f;
    unsigned r = v.u + 0x7FFF + ((v.u >> 16) & 1);  // round-to-nearest-even
    return (short)(r >> 16);
}

DEV float bf2f(unsigned short b) {
    union { unsigned u; float f; } v; v.u = ((unsigned)b) << 16;
    return v.f;
}

DEV unsigned pack2bf(float a, float b) {
    return ((unsigned)(unsigned short)f2bf(a)) | (((unsigned)(unsigned short)f2bf(b)) << 16);
}

DEV void gload_lds16(const void* g, void* lds) {
    __builtin_amdgcn_global_load_lds(
        (const __attribute__((address_space(1))) void*)g,
        (__attribute__((address_space(3))) void*)lds, 16, 0, 0);
}

// ---------------- conv1: (B,1,512,200) -> (B,8,512,25), k=15 stride=8 pad=7 ----------------
__global__ void conv1_kernel(const float* __restrict__ x, const float* __restrict__ w,
                             const float* __restrict__ bias, float* __restrict__ out) {
    int idx = blockIdx.x * blockDim.x + threadIdx.x;
    const int total = 8 * 8 * 512 * 25;
    if (idx >= total) return;
    int ow = idx % 25;
    int p  = (idx / 25) % 512;
    int oc = (idx / (25 * 512)) % 8;
    int b  = idx / (25 * 512 * 8);
    const float* xp = x + b * 512 * 200 + p * 200;
    const float* wp = w + oc * 15;
    float acc = bias[oc];
    int t0 = ow * 8 - 7;
#pragma unroll
    for (int k = 0; k < 15; k++) {
        int t = t0 + k;
        if (t >= 0 && t < 200) acc += wp[k] * xp[t];
    }
    out[idx] = acc;
}

// ---------------- conv 1x3 (pad 1) on (B,8,512,25) ----------------
__global__ void conv3x1_kernel(const float* __restrict__ in, const float* __restrict__ w,
                               const float* __restrict__ bias, float* __restrict__ out) {
    int idx = blockIdx.x * blockDim.x + threadIdx.x;
    const int total = 8 * 8 * 512 * 25;
    if (idx >= total) return;
    int ow = idx % 25;
    int p  = (idx / 25) % 512;
    int oc = (idx / 12800) & 7;
    int b  = idx / 102400;
    float acc = bias[oc];
#pragma unroll
    for (int ic = 0; ic < 8; ic++) {
        const float* ip = in + b * 102400 + ic * 12800 + p * 25;
        const float* wp = w + oc * 24 + ic * 3;
        if (ow > 0)  acc += wp[0] * ip[ow - 1];
        acc += wp[1] * ip[ow];
        if (ow < 24) acc += wp[2] * ip[ow + 1];
    }
    out[idx] = acc;
}

// ---------------- groupnorm ----------------
__global__ void gn_stats_kernel(const float* __restrict__ buf, float* __restrict__ stats) {
    int b = blockIdx.x >> 2, g = blockIdx.x & 3;
    const float* base = buf + b * 102400 + g * 2 * 12800;
    float s = 0.f, s2 = 0.f;
    for (int l = threadIdx.x; l < 25600; l += 256) {
        float v = base[l];
        s += v; s2 += v * v;
    }
    __shared__ float ss[256], ss2[256];
    ss[threadIdx.x] = s; ss2[threadIdx.x] = s2;
    __syncthreads();
    for (int o = 128; o; o >>= 1) {
        if (threadIdx.x < o) { ss[threadIdx.x] += ss[threadIdx.x + o]; ss2[threadIdx.x] += ss2[threadIdx.x + o]; }
        __syncthreads();
    }
    if (threadIdx.x == 0) {
        float m = ss[0] / 25600.f;
        float v = ss2[0] / 25600.f - m * m;
        stats[blockIdx.x * 2] = m;
        stats[blockIdx.x * 2 + 1] = v;
    }
}

__global__ void gn_apply_kernel(float* __restrict__ buf, const float* __restrict__ stats,
                                const float* __restrict__ g, const float* __restrict__ bb) {
    int idx = blockIdx.x * blockDim.x + threadIdx.x;
    if (idx >= 8 * 102400) return;
    int c = (idx / 12800) & 7;
    int b = idx / 102400;
    int grp = c >> 1;
    float m = stats[(b * 4 + grp) * 2];
    float v = stats[(b * 4 + grp) * 2 + 1];
    float val = (buf[idx] - m) * rsqrtf(v + 1e-5f) * g[c] + bb[c];
    buf[idx] = gelu_exact(val);
}

// ---------------- embed ----------------
__global__ void embed_kernel(const float* __restrict__ conv, const float* __restrict__ cls,
                             const float* __restrict__ pos, const float* __restrict__ te,
                             float* __restrict__ h) {
    int idx = blockIdx.x * blockDim.x + threadIdx.x;
    if (idx >= 8 * 513 * 200) return;
    int d = idx % 200;
    int n = (idx / 200) % 513;
    int b = idx / (200 * 513);
    float val;
    if (n == 0) {
        val = cls[d] + pos[d];
    } else {
        int p = n - 1;
        int t = d >> 3;
        int c = d & 7;
        val = conv[b * 102400 + c * 12800 + p * 25 + t];
        int ch = p >> 3, tw = p & 7;
        val += pos[(1 + ch) * 200 + d] + te[tw * 200 + d];
    }
    h[idx] = val;
}

// ---------------- weight convert+pad (vec4): fp32 [R][K] -> bf16 [R][KP] ----------------
__global__ void convpad_kernel(const float* __restrict__ src, short* __restrict__ dst,
                               int R, int K, int KP) {
    int idx = blockIdx.x * blockDim.x + threadIdx.x;
    int total = R * (KP >> 2);
    if (idx >= total) return;
    int r = idx / (KP >> 2);
    int c4 = (idx - r * (KP >> 2)) << 2;
    short4 o;
    if (c4 + 3 < K) {
        float4 f = *(const float4*)&src[(size_t)r * K + c4];
        o.x = f2bf(f.x); o.y = f2bf(f.y); o.z = f2bf(f.z); o.w = f2bf(f.w);
    } else {
        o.x = (c4 + 0 < K) ? f2bf(src[(size_t)r * K + c4 + 0]) : (short)0;
        o.y = (c4 + 1 < K) ? f2bf(src[(size_t)r * K + c4 + 1]) : (short)0;
        o.z = (c4 + 2 < K) ? f2bf(src[(size_t)r * K + c4 + 2]) : (short)0;
        o.w = (c4 + 3 < K) ? f2bf(src[(size_t)r * K + c4 + 3]) : (short)0;
    }
    *(short4*)&dst[(size_t)r * KP + c4] = o;
}

// ---------------- bias precompute via LDS table (uint2 stores, unroll 2) ----------------
__global__ __launch_bounds__(256) void bias_lds_kernel(const float* __restrict__ table,
                                                       const int* __restrict__ ridx,
                                                       short* __restrict__ bias) {
    __shared__ float tl[1908];
    const int qt = blockIdx.x, hh = blockIdx.y, d = blockIdx.z;
    const float* tab = table + d * 19080;
    for (int i = threadIdx.x; i < 1908; i += 256) tl[i] = tab[i * 10 + hh];
    __syncthreads();
    const int q0 = qt * 64;
    const int nrows = min(64, 513 - q0);
    short* obase = bias + ((size_t)d * 10 + hh) * 513 * 576;
#pragma unroll 2
    for (int lin = threadIdx.x; lin < nrows * 144; lin += 256) {
        int r = lin / 144, j = lin % 144;
        int q = q0 + r;
        const int* rp = ridx + q * 513;
        int k0 = j * 4;
        float v[4];
#pragma unroll
        for (int e = 0; e < 4; e++) {
            int k = k0 + e;
            v[e] = (k < 513) ? tl[rp[k]] : 0.f;
        }
        uint2 pk;
        pk.x = pack2bf(v[0], v[1]);
        pk.y = pack2bf(v[2], v[3]);
        *(uint2*)&obase[(size_t)q * 576 + k0] = pk;
    }
}

// ---------------- LayerNorm over D=200; 4 rows per 256-thr block (one wave/row) ----------
__global__ __launch_bounds__(256) void ln_kernel(const float* __restrict__ in,
                                                 const float* __restrict__ g,
                                                 const float* __restrict__ b,
                                                 short* __restrict__ out) {
    int row = blockIdx.x * 4 + (threadIdx.x >> 6);
    int lane = threadIdx.x & 63;
    const float* x = in + (size_t)row * 200;
    float v[4];
    float s = 0.f;
#pragma unroll
    for (int i = 0; i < 4; i++) {
        int d = lane + i * 64;
        v[i] = (d < 200) ? x[d] : 0.f;
        s += v[i];
    }
#pragma unroll
    for (int o = 32; o; o >>= 1) s += __shfl_xor(s, o);
    float mean = s * (1.f / 200.f);
    float s2 = 0.f;
#pragma unroll
    for (int i = 0; i < 4; i++) {
        int d = lane + i * 64;
        float dv = (d < 200) ? (v[i] - mean) : 0.f;
        s2 += dv * dv;
    }
#pragma unroll
    for (int o = 32; o; o >>= 1) s2 += __shfl_xor(s2, o);
    float rstd = rsqrtf(s2 * (1.f / 200.f) + 1e-6f);
#pragma unroll
    for (int i = 0; i < 4; i++) {
        int d = lane + i * 64;
        float val = (d < 200) ? (v[i] - mean) * rstd * g[d] + b[d] : 0.f;
        out[(size_t)row * 256 + d] = f2bf(val);
    }
}

// ---------------- 4-deep pipelined GEMM for KP=256: all loads up-front ----------------
// BM=BN=64, 4 waves 2x2 (wave tile 32x32). All 16 staging loads issued at kernel start
// into 4 LDS stages (64 KB); stage s consumed after counted vmcnt((3-s)*4) + one barrier.
// Pays global latency once per block instead of once per k-step; no LDS reuse -> 1 barrier/step.
// EPI 1: Cf = res + gamma[n]*(acc+bias[n])
// EPI 2: Cb = bf16(gelu(acc+bias[n])), zero pad cols N..NPout
// EPI 3: qkv scatter -> Qb (scaled), Kb, Vt
template <int EPI>
__global__ __launch_bounds__(256) void gemm_pipe(const short* __restrict__ A,
                                                 const short* __restrict__ W,
                                                 float* __restrict__ Cf,
                                                 short* __restrict__ Cb,
                                                 const float* __restrict__ res,
                                                 const float* __restrict__ bias,
                                                 const float* __restrict__ gamma,
                                                 int M, int N, int ldc, int NPout,
                                                 short* __restrict__ Qb = nullptr,
                                                 short* __restrict__ Kb = nullptr,
                                                 short* __restrict__ Vt = nullptr) {
    __shared__ __align__(16) short Ss[4][128 * 64];   // 4 stages x 16 KB

    const int tid = threadIdx.x;
    const int w = tid >> 6, l = tid & 63;
    const int wm = (w >> 1) * 32, wn = (w & 1) * 32;
    const int bm = blockIdx.y * 64, bn = blockIdx.x * 64;

    // issue ALL staging loads (4 per stage per thread; stage order = vmcnt order)
#pragma unroll
    for (int s = 0; s < 4; s++) {
#pragma unroll
        for (int it = 0; it < 4; it++) {
            int lin = it * 256 + tid;
            int row = lin >> 3, slot = lin & 7;
            int srcslot = slot ^ (row & 7);
            const short* g;
            if (row < 64) g = A + (size_t)(bm + row) * 256 + s * 64 + srcslot * 8;
            else          g = W + (size_t)(bn + row - 64) * 256 + s * 64 + srcslot * 8;
            gload_lds16(g, (char*)Ss[s] + lin * 16);
        }
    }

    f32x4 acc[2][2] = {};
#pragma unroll
    for (int s = 0; s < 4; s++) {
        if (s == 0)      asm volatile("s_waitcnt vmcnt(12)" ::: "memory");
        else if (s == 1) asm volatile("s_waitcnt vmcnt(8)" ::: "memory");
        else if (s == 2) asm volatile("s_waitcnt vmcnt(4)" ::: "memory");
        else             asm volatile("s_waitcnt vmcnt(0)" ::: "memory");
        __builtin_amdgcn_s_barrier();

        const char* Sc = (const char*)Ss[s];
#pragma unroll
        for (int kk = 0; kk < 2; kk++) {
            const int kbyte = kk * 64 + (l >> 4) * 16;
            bf16x8 af[2], bfr[2];
#pragma unroll
            for (int i = 0; i < 2; i++) {
                int r = wm + i * 16 + (l & 15);
                af[i] = *(const bf16x8*)(Sc + r * 128 + (kbyte ^ ((r & 7) << 4)));
            }
#pragma unroll
            for (int j = 0; j < 2; j++) {
                int r = 64 + wn + j * 16 + (l & 15);
                bfr[j] = *(const bf16x8*)(Sc + r * 128 + (kbyte ^ ((r & 7) << 4)));
            }
#pragma unroll
            for (int i = 0; i < 2; i++)
#pragma unroll
                for (int j = 0; j < 2; j++)
                    acc[i][j] = __builtin_amdgcn_mfma_f32_16x16x32_bf16(af[i], bfr[j], acc[i][j], 0, 0, 0);
        }
    }

    const int col0 = bn + wn + (l & 15);
    const int rbase = (l >> 4) * 4;
#pragma unroll
    for (int i = 0; i < 2; i++) {
#pragma unroll
        for (int r = 0; r < 4; r++) {
            int gm = bm + wm + i * 16 + rbase + r;
            if (gm >= M) continue;
#pragma unroll
            for (int j = 0; j < 2; j++) {
                int gn = col0 + j * 16;
                float v = acc[i][j][r];
                if (EPI == 1) {
                    if (gn < N) Cf[(size_t)gm * ldc + gn] =
                        res[(size_t)gm * ldc + gn] + gamma[gn] * (v + bias[gn]);
                } else if (EPI == 2) {
                    if (gn < NPout)
                        Cb[(size_t)gm * ldc + gn] = (gn < N) ? f2bf(gelu_exact(v + bias[gn])) : (short)0;
                } else {  // EPI 3: qkv scatter
                    if (gn < 600) {
                        int bb2 = gm / 513, n = gm - bb2 * 513;
                        if (gn < 200) {
                            int hq = gn / 20, dq = gn - hq * 20;
                            Qb[((size_t)(bb2 * 10 + hq) * 576 + n) * 32 + dq] =
                                f2bf(v * 0.22360679774997896f);
                        } else if (gn < 400) {
                            int gk = gn - 200, hk = gk / 20, dk = gk - hk * 20;
                            Kb[((size_t)(bb2 * 10 + hk) * 576 + n) * 32 + dk] = f2bf(v);
                        } else {
                            int gv = gn - 400, hv = gv / 20, dv2 = gv - hv * 20;
                            Vt[((size_t)(bb2 * 10 + hv) * 32 + dv2) * 576 + n] = f2bf(v);
                        }
                    }
                }
            }
        }
    }
}

// ---------------- bf16 MFMA GEMM, double-buffered K-loop (fc2, KP=832) ----------------
// EPI 1: Cf = res + gamma[n]*(acc+bias[n])
template <int EPI, int BM, int BN>
__global__ __launch_bounds__(256) void gemm_bf(const short* __restrict__ A,
                                               const short* __restrict__ W,
                                               float* __restrict__ Cf,
                                               short* __restrict__ Cb,
                                               const float* __restrict__ res,
                                               const float* __restrict__ bias,
                                               const float* __restrict__ gamma,
                                               int M, int N, int KP, int ldc, int NPout) {
    constexpr int WM = BM / 2, WN = BN / 2;
    constexpr int AM = WM / 16, BNr = WN / 16;
    constexpr int LOADS = (BM + BN) / 32;
    __shared__ __align__(16) short Ss[2][(BM + BN) * 64];

    const int tid = threadIdx.x;
    const int w = tid >> 6, l = tid & 63;
    const int wm = (w >> 1) * WM, wn = (w & 1) * WN;
    const int bm = blockIdx.y * BM, bn = blockIdx.x * BN;

    f32x4 acc[AM][BNr] = {};

    auto stage = [&](int buf, int k0) {
#pragma unroll
        for (int it = 0; it < LOADS; it++) {
            int lin = it * 256 + tid;
            int row = lin >> 3, slot = lin & 7;
            int srcslot = slot ^ (row & 7);
            const short* g;
            if (it * 32 < BM) {
                g = A + (size_t)(bm + row) * KP + k0 + srcslot * 8;
            } else {
                g = W + (size_t)(bn + row - BM) * KP + k0 + srcslot * 8;
            }
            gload_lds16(g, (char*)Ss[buf] + lin * 16);
        }
    };

    const int nk = KP >> 6;
    stage(0, 0);
    int cur = 0;
    for (int kstep = 0; kstep < nk; kstep++) {
        if (kstep + 1 < nk) {
            stage(cur ^ 1, (kstep + 1) << 6);
            if constexpr (LOADS == 6) asm volatile("s_waitcnt vmcnt(6)" ::: "memory");
            else                      asm volatile("s_waitcnt vmcnt(4)" ::: "memory");
        } else {
            asm volatile("s_waitcnt vmcnt(0)" ::: "memory");
        }
        __builtin_amdgcn_s_barrier();

        const char* Sc = (const char*)Ss[cur];
#pragma unroll
        for (int kk = 0; kk < 2; kk++) {
            const int kbyte = kk * 64 + (l >> 4) * 16;
            bf16x8 af[AM], bfr[BNr];
#pragma unroll
            for (int i = 0; i < AM; i++) {
                int r = wm + i * 16 + (l & 15);
                af[i] = *(const bf16x8*)(Sc + r * 128 + (kbyte ^ ((r & 7) << 4)));
            }
#pragma unroll
            for (int j = 0; j < BNr; j++) {
                int r = BM + wn + j * 16 + (l & 15);
                bfr[j] = *(const bf16x8*)(Sc + r * 128 + (kbyte ^ ((r & 7) << 4)));
            }
#pragma unroll
            for (int i = 0; i < AM; i++)
#pragma unroll
                for (int j = 0; j < BNr; j++)
                    acc[i][j] = __builtin_amdgcn_mfma_f32_16x16x32_bf16(af[i], bfr[j], acc[i][j], 0, 0, 0);
        }
        __builtin_amdgcn_s_barrier();
        cur ^= 1;
    }

    const int col0 = bn + wn + (l & 15);
    const int rbase = (l >> 4) * 4;
#pragma unroll
    for (int i = 0; i < AM; i++) {
#pragma unroll
        for (int r = 0; r < 4; r++) {
            int gm = bm + wm + i * 16 + rbase + r;
            if (gm >= M) continue;
#pragma unroll
            for (int j = 0; j < BNr; j++) {
                int gn = col0 + j * 16;
                float v = acc[i][j][r];
                if (EPI == 1) {
                    if (gn < N) Cf[(size_t)gm * ldc + gn] =
                        res[(size_t)gm * ldc + gn] + gamma[gn] * (v + bias[gn]);
                } else if (EPI == 2) {
                    if (gn < NPout)
                        Cb[(size_t)gm * ldc + gn] = (gn < N) ? f2bf(gelu_exact(v + bias[gn])) : (short)0;
                }
            }
        }
    }
}

// ---------------- MFMA flash attention: dbuf K/V staging, bias direct-to-register -------
__global__ __launch_bounds__(256) void attn_mfma2(const short* __restrict__ Qb,
                                                  const short* __restrict__ Kb,
                                                  const short* __restrict__ Vt,
                                                  const short* __restrict__ biasb,
                                                  short* __restrict__ ob) {
    __shared__ __align__(16) short Klds[2][64 * 32];
    __shared__ __align__(16) short Vlds[2][32 * 64];
    __shared__ __align__(16) short Pl[4 * 16 * 72];

    const int orig = blockIdx.x;
    const int wg = (orig & 7) * 90 + (orig >> 3);   // XCD-chunked bijection (720 = 8*90)
    const int hh = wg / 72;
    const int rem = wg % 72;
    const int qt = rem >> 3, b = rem & 7;

    const int t = threadIdx.x, wave = t >> 6, l = t & 63;
    const int lq = l & 15, hi = l >> 4;
    const int n = qt * 64 + wave * 16 + lq;
    const int nc = min(n, 512);

    const size_t bh = (size_t)(b * 10 + hh);
    const short* Kbase = Kb + bh * 576 * 32;
    const short* Vbase = Vt + bh * 32 * 576;
    const short* Brow  = biasb + ((size_t)hh * 513 + nc) * 576;

    bf16x8 qf = *(const bf16x8*)&Qb[(bh * 576 + nc) * 32 + hi * 8];

    const int krow = t >> 2, kch = t & 3;
    const short* ksrc = Kbase + (size_t)krow * 32 + (kch ^ ((krow >> 2) & 3)) * 8;
    const int vrow = t >> 3, vch = t & 7;
    const short* vsrc = Vbase + (size_t)vrow * 576 + (vch ^ (vrow & 7)) * 8;

    float mrun = -1e30f, lsum = 0.f;
    f32x4 oacc0 = {}, oacc1 = {};
    const f32x4 zero4 = {};

    gload_lds16(ksrc, (char*)Klds[0] + t * 16);
    gload_lds16(vsrc, (char*)Vlds[0] + t * 16);

    int cur = 0;
    for (int kt = 0; kt < 9; kt++) {
        const int koff = kt * 64;

        uint2 bl[4];
#pragma unroll
        for (int c = 0; c < 4; c++)
            bl[c] = *(const uint2*)&Brow[koff + c * 16 + hi * 4];

        if (kt < 8) {
            const int knext = koff + 64;
            gload_lds16(ksrc + (size_t)knext * 32, (char*)Klds[cur ^ 1] + t * 16);
            gload_lds16(vsrc + knext, (char*)Vlds[cur ^ 1] + t * 16);
            asm volatile("s_waitcnt vmcnt(2)" ::: "memory");
        } else {
            asm volatile("s_waitcnt vmcnt(0)" ::: "memory");
        }
        __builtin_amdgcn_s_barrier();

        const short* Kc = Klds[cur];
        const short* Vc = Vlds[cur];

        f32x4 s[4];
        __builtin_amdgcn_s_setprio(1);
#pragma unroll
        for (int c = 0; c < 4; c++) {
            int r = c * 16 + lq;
            bf16x8 kf = *(const bf16x8*)((const char*)Kc + r * 64 + ((hi ^ ((lq >> 2) & 3)) << 4));
            s[c] = __builtin_amdgcn_mfma_f32_16x16x32_bf16(kf, qf, zero4, 0, 0, 0);
        }
        __builtin_amdgcn_s_setprio(0);

        float sv[4][4];
        float tm = -1e30f;
#pragma unroll
        for (int c = 0; c < 4; c++) {
            float bv[4] = { bf2f((unsigned short)(bl[c].x & 0xFFFF)), bf2f((unsigned short)(bl[c].x >> 16)),
                            bf2f((unsigned short)(bl[c].y & 0xFFFF)), bf2f((unsigned short)(bl[c].y >> 16)) };
            int kglob = koff + c * 16 + hi * 4;
#pragma unroll
            for (int r = 0; r < 4; r++) {
                float val = s[c][r] + bv[r];
                if (kglob + r > 512) val = -1e30f;
                sv[c][r] = val;
                tm = fmaxf(tm, val);
            }
        }
        tm = fmaxf(tm, __shfl_xor(tm, 16));
        tm = fmaxf(tm, __shfl_xor(tm, 32));
        float mnew = fmaxf(mrun, tm);
        float resc = __expf(mrun - mnew);
        mrun = mnew;

        float ts = 0.f;
#pragma unroll
        for (int c = 0; c < 4; c++) {
            float p0 = __expf(sv[c][0] - mnew);
            float p1 = __expf(sv[c][1] - mnew);
            float p2 = __expf(sv[c][2] - mnew);
            float p3 = __expf(sv[c][3] - mnew);
            ts += (p0 + p1) + (p2 + p3);
            uint2 pk;
            pk.x = pack2bf(p0, p1);
            pk.y = pack2bf(p2, p3);
            *(uint2*)&Pl[wave * 1152 + lq * 72 + c * 16 + hi * 4] = pk;
        }
        ts += __shfl_xor(ts, 16);
        ts += __shfl_xor(ts, 32);
        lsum = lsum * resc + ts;
        oacc0 *= resc;
        oacc1 *= resc;

        __builtin_amdgcn_s_setprio(1);
#pragma unroll
        for (int kc = 0; kc < 2; kc++) {
            bf16x8 pf = *(const bf16x8*)&Pl[wave * 1152 + lq * 72 + kc * 32 + hi * 8];
            bf16x8 vf0 = *(const bf16x8*)((const char*)Vc + lq * 128 +
                                          (((kc * 4 + hi) ^ (lq & 7)) << 4));
            bf16x8 vf1 = *(const bf16x8*)((const char*)Vc + (16 + lq) * 128 +
                                          (((kc * 4 + hi) ^ (lq & 7)) << 4));
            oacc0 = __builtin_amdgcn_mfma_f32_16x16x32_bf16(vf0, pf, oacc0, 0, 0, 0);
            oacc1 = __builtin_amdgcn_mfma_f32_16x16x32_bf16(vf1, pf, oacc1, 0, 0, 0);
        }
        __builtin_amdgcn_s_setprio(0);

        __builtin_amdgcn_s_barrier();
        cur ^= 1;
    }

    if (n < 513) {
        float inv = 1.f / lsum;
        short* op = ob + (size_t)(b * 513 + n) * 256 + hh * 20;
        {
            uint2 pk;
            pk.x = pack2bf(oacc0[0] * inv, oacc0[1] * inv);
            pk.y = pack2bf(oacc0[2] * inv, oacc0[3] * inv);
            *(uint2*)&op[hi * 4] = pk;
        }
        if (hi == 0) {
            uint2 pk;
            pk.x = pack2bf(oacc1[0] * inv, oacc1[1] * inv);
            pk.y = pack2bf(oacc1[2] * inv, oacc1[3] * inv);
            *(uint2*)&op[16] = pk;
        }
    }
}

// ---------------- final: mean-pool patches -> LN -> head (200 -> 4) ----------------
__global__ __launch_bounds__(256) void final_kernel(const float* __restrict__ h,
                                                    const float* __restrict__ g,
                                                    const float* __restrict__ bb,
                                                    const float* __restrict__ hw,
                                                    const float* __restrict__ hb,
                                                    float* __restrict__ out) {
    __shared__ float pool[256];
    __shared__ float red[256];
    int b = blockIdx.x, t = threadIdx.x;
    float s = 0.f;
    if (t < 200) {
        const float* hp = h + b * 513 * 200 + 200 + t;
        for (int p = 0; p < 512; p++) s += hp[p * 200];
        s *= (1.f / 512.f);
    }
    pool[t] = (t < 200) ? s : 0.f;
    red[t] = pool[t];
    __syncthreads();
    for (int o = 128; o; o >>= 1) {
        if (t < o) red[t] += red[t + o];
        __syncthreads();
    }
    float mean = red[0] / 200.f;
    __syncthreads();
    float dv = (t < 200) ? (pool[t] - mean) : 0.f;
    red[t] = dv * dv;
    __syncthreads();
    for (int o = 128; o; o >>= 1) {
        if (t < o) red[t] += red[t + o];
        __syncthreads();
    }
    float var = red[0] / 200.f;
    float rstd = rsqrtf(var + 1e-6f);
    __syncthreads();
    if (t < 200) pool[t] = (pool[t] - mean) * rstd * g[t] + bb[t];
    __syncthreads();
    if (t < 4) {
        float acc = hb[t];
        for (int d2 = 0; d2 < 200; d2++) acc += pool[d2] * hw[t * 200 + d2];
        out[b * 4 + t] = acc;
    }
}

extern "C" void kernel_launch(void* const* d_in, const int* in_sizes, int n_in,
                              void* d_out, int out_size, void* d_ws, size_t ws_size,
                              hipStream_t stream) {
    const float* x        = (const float*)d_in[0];
    const float* conv1_w  = (const float*)d_in[1];
    const float* conv1_b  = (const float*)d_in[2];
    const float* gn1_g    = (const float*)d_in[3];
    const float* gn1_b    = (const float*)d_in[4];
    const float* conv2_w  = (const float*)d_in[5];
    const float* conv2_b  = (const float*)d_in[6];
    const float* gn2_g    = (const float*)d_in[7];
    const float* gn2_b    = (const float*)d_in[8];
    const float* conv3_w  = (const float*)d_in[9];
    const float* conv3_b  = (const float*)d_in[10];
    const float* gn3_g    = (const float*)d_in[11];
    const float* gn3_b    = (const float*)d_in[12];
    const float* cls_tok  = (const float*)d_in[13];
    const float* pos_emb  = (const float*)d_in[14];
    const float* time_emb = (const float*)d_in[15];
    const float* ln1_g    = (const float*)d_in[16];
    const float* ln1_b    = (const float*)d_in[17];
    const float* qkv_w    = (const float*)d_in[18];
    const float* rel_tab  = (const float*)d_in[19];
    const float* proj_w   = (const float*)d_in[20];
    const float* proj_b   = (const float*)d_in[21];
    const float* gamma1   = (const float*)d_in[22];
    const float* ln2_g    = (const float*)d_in[23];
    const float* ln2_b    = (const float*)d_in[24];
    const float* fc1_w    = (const float*)d_in[25];
    const float* fc1_b    = (const float*)d_in[26];
    const float* fc2_w    = (const float*)d_in[27];
    const float* fc2_b    = (const float*)d_in[28];
    const float* gamma2   = (const float*)d_in[29];
    const float* fcn_g    = (const float*)d_in[30];
    const float* fcn_b    = (const float*)d_in[31];
    const float* head_w   = (const float*)d_in[32];
    const float* head_b   = (const float*)d_in[33];
    const int*   rel_idx  = (const int*)d_in[34];

    // ---- workspace layout (bytes), total ~102 MB ----
    char* p = (char*)d_ws;
    float* h    = (float*)p; p += 3283200;          // 8*513*200 f32
    char* qreg = p;                                  // multi-phase region
    float* c1   = (float*)qreg;
    float* c2   = c1 + 819200;
    short* Qb   = (short*)qreg;                     // [8][10][576][32]
    short* Kb   = Qb + 1474560;
    short* Vt   = Kb + 1474560;                     // [8][10][32][576]
    short* mlp  = (short*)qreg;                     // [4104][832] (MLP phase)
    p += 9849600;
    short* y    = (short*)p; p += 2101248;          // 4104*256 bf16
    short* ob   = (short*)p; p += 2101248;          // 4104*256 bf16
    short* wqkv = (short*)p; p += 3686400;
    short* wproj= (short*)p; p += 1228800;
    short* wfc1 = (short*)p; p += 4915200;
    short* wfc2 = (short*)p; p += 3993600;
    short* biasb= (short*)p; p += 12 * 5909760;     // [12][10][513][576] bf16 = 70.9 MB
    float* stats= (float*)p;

    // ---- upfront precompute ----
    convpad_kernel<<<(7200 * 64 + 255) / 256, 256, 0, stream>>>(qkv_w, wqkv, 7200, 200, 256);
    convpad_kernel<<<(2400 * 64 + 255) / 256, 256, 0, stream>>>(proj_w, wproj, 2400, 200, 256);
    convpad_kernel<<<(9600 * 64 + 255) / 256, 256, 0, stream>>>(fc1_w, wfc1, 9600, 200, 256);
    convpad_kernel<<<(2400 * 208 + 255) / 256, 256, 0, stream>>>(fc2_w, wfc2, 2400, 800, 832);
    bias_lds_kernel<<<dim3(9, 10, 12), 256, 0, stream>>>(rel_tab, rel_idx, biasb);
    hipMemsetAsync(ob, 0, 2101248, stream);

    // ---- patch embed ----
    conv1_kernel<<<3200, 256, 0, stream>>>(x, conv1_w, conv1_b, c1);
    gn_stats_kernel<<<32, 256, 0, stream>>>(c1, stats);
    gn_apply_kernel<<<3200, 256, 0, stream>>>(c1, stats, gn1_g, gn1_b);
    conv3x1_kernel<<<3200, 256, 0, stream>>>(c1, conv2_w, conv2_b, c2);
    gn_stats_kernel<<<32, 256, 0, stream>>>(c2, stats);
    gn_apply_kernel<<<3200, 256, 0, stream>>>(c2, stats, gn2_g, gn2_b);
    conv3x1_kernel<<<3200, 256, 0, stream>>>(c2, conv3_w, conv3_b, c1);
    gn_stats_kernel<<<32, 256, 0, stream>>>(c1, stats);
    gn_apply_kernel<<<3200, 256, 0, stream>>>(c1, stats, gn3_g, gn3_b);
    embed_kernel<<<(820800 + 255) / 256, 256, 0, stream>>>(c1, cls_tok, pos_emb, time_emb, h);

    hipMemsetAsync(Qb, 0, 3 * 1474560 * 2, stream);  // zero QKV pad regions (post conv phase)

    // ---- transformer layers ----
    for (int d = 0; d < 12; d++) {
        ln_kernel<<<1026, 256, 0, stream>>>(h, ln1_g + d * 200, ln1_b + d * 200, y);
        gemm_pipe<3><<<dim3(10, 65), 256, 0, stream>>>(y, wqkv + d * 153600,
                                                       nullptr, nullptr, nullptr, nullptr, nullptr,
                                                       4104, 600, 0, 0, Qb, Kb, Vt);
        attn_mfma2<<<720, 256, 0, stream>>>(Qb, Kb, Vt, biasb + (size_t)d * 2954880, ob);
        gemm_pipe<1><<<dim3(4, 65), 256, 0, stream>>>(ob, wproj + d * 51200, h, nullptr,
                                                      h, proj_b + d * 200, gamma1 + d * 200,
                                                      4104, 200, 200, 0);
        ln_kernel<<<1026, 256, 0, stream>>>(h, ln2_g + d * 200, ln2_b + d * 200, y);
        gemm_pipe<2><<<dim3(13, 65), 256, 0, stream>>>(y, wfc1 + d * 204800, nullptr, mlp,
                                                       nullptr, fc1_b + d * 800, nullptr,
                                                       4104, 800, 832, 832);
        gemm_bf<1, 64, 64><<<dim3(4, 65), 256, 0, stream>>>(mlp, wfc2 + d * 166400, h, nullptr,
                                                            h, fc2_b + d * 200, gamma2 + d * 200,
                                                            4104, 200, 832, 200, 0);
    }

    // ---- pool + head ----
    final_kernel<<<8, 256, 0, stream>>>(h, fcn_g, fcn_b, head_w, head_b, (float*)d_out);
}

// Round 14
// 1037.116 us; speedup vs baseline: 1.0603x; 1.0603x over previous
//
#include <hip/hip_runtime.h>
#include <math.h>

#define DEV static __device__ __forceinline__

typedef __attribute__((ext_vector_type(8))) short bf16x8;
typedef __attribute__((ext_vector_type(4))) float f32x4;

DEV float gelu_exact(float x) {
    return 0.5f * x * (1.0f + erff(x * 0.70710678118654752f));
}

DEV short f2bf(float f) {
    union { float f; unsigned u; } v; v.f = f;
    unsigned r = v.u + 0x7FFF + ((v.u >> 16) & 1);  // round-to-nearest-even
    return (short)(r >> 16);
}

DEV float bf2f(unsigned short b) {
    union { unsigned u; float f; } v; v.u = ((unsigned)b) << 16;
    return v.f;
}

DEV unsigned pack2bf(float a, float b) {
    return ((unsigned)(unsigned short)f2bf(a)) | (((unsigned)(unsigned short)f2bf(b)) << 16);
}

DEV void gload_lds16(const void* g, void* lds) {
    __builtin_amdgcn_global_load_lds(
        (const __attribute__((address_space(1))) void*)g,
        (__attribute__((address_space(3))) void*)lds, 16, 0, 0);
}

// ---------------- conv1: (B,1,512,200) -> (B,8,512,25), k=15 stride=8 pad=7 ----------------
__global__ void conv1_kernel(const float* __restrict__ x, const float* __restrict__ w,
                             const float* __restrict__ bias, float* __restrict__ out) {
    int idx = blockIdx.x * blockDim.x + threadIdx.x;
    const int total = 8 * 8 * 512 * 25;
    if (idx >= total) return;
    int ow = idx % 25;
    int p  = (idx / 25) % 512;
    int oc = (idx / (25 * 512)) % 8;
    int b  = idx / (25 * 512 * 8);
    const float* xp = x + b * 512 * 200 + p * 200;
    const float* wp = w + oc * 15;
    float acc = bias[oc];
    int t0 = ow * 8 - 7;
#pragma unroll
    for (int k = 0; k < 15; k++) {
        int t = t0 + k;
        if (t >= 0 && t < 200) acc += wp[k] * xp[t];
    }
    out[idx] = acc;
}

// ---------------- conv 1x3 (pad 1) on (B,8,512,25) ----------------
__global__ void conv3x1_kernel(const float* __restrict__ in, const float* __restrict__ w,
                               const float* __restrict__ bias, float* __restrict__ out) {
    int idx = blockIdx.x * blockDim.x + threadIdx.x;
    const int total = 8 * 8 * 512 * 25;
    if (idx >= total) return;
    int ow = idx % 25;
    int p  = (idx / 25) % 512;
    int oc = (idx / 12800) & 7;
    int b  = idx / 102400;
    float acc = bias[oc];
#pragma unroll
    for (int ic = 0; ic < 8; ic++) {
        const float* ip = in + b * 102400 + ic * 12800 + p * 25;
        const float* wp = w + oc * 24 + ic * 3;
        if (ow > 0)  acc += wp[0] * ip[ow - 1];
        acc += wp[1] * ip[ow];
        if (ow < 24) acc += wp[2] * ip[ow + 1];
    }
    out[idx] = acc;
}

// ---------------- groupnorm ----------------
__global__ void gn_stats_kernel(const float* __restrict__ buf, float* __restrict__ stats) {
    int b = blockIdx.x >> 2, g = blockIdx.x & 3;
    const float* base = buf + b * 102400 + g * 2 * 12800;
    float s = 0.f, s2 = 0.f;
    for (int l = threadIdx.x; l < 25600; l += 256) {
        float v = base[l];
        s += v; s2 += v * v;
    }
    __shared__ float ss[256], ss2[256];
    ss[threadIdx.x] = s; ss2[threadIdx.x] = s2;
    __syncthreads();
    for (int o = 128; o; o >>= 1) {
        if (threadIdx.x < o) { ss[threadIdx.x] += ss[threadIdx.x + o]; ss2[threadIdx.x] += ss2[threadIdx.x + o]; }
        __syncthreads();
    }
    if (threadIdx.x == 0) {
        float m = ss[0] / 25600.f;
        float v = ss2[0] / 25600.f - m * m;
        stats[blockIdx.x * 2] = m;
        stats[blockIdx.x * 2 + 1] = v;
    }
}

__global__ void gn_apply_kernel(float* __restrict__ buf, const float* __restrict__ stats,
                                const float* __restrict__ g, const float* __restrict__ bb) {
    int idx = blockIdx.x * blockDim.x + threadIdx.x;
    if (idx >= 8 * 102400) return;
    int c = (idx / 12800) & 7;
    int b = idx / 102400;
    int grp = c >> 1;
    float m = stats[(b * 4 + grp) * 2];
    float v = stats[(b * 4 + grp) * 2 + 1];
    float val = (buf[idx] - m) * rsqrtf(v + 1e-5f) * g[c] + bb[c];
    buf[idx] = gelu_exact(val);
}

// ---------------- embed ----------------
__global__ void embed_kernel(const float* __restrict__ conv, const float* __restrict__ cls,
                             const float* __restrict__ pos, const float* __restrict__ te,
                             float* __restrict__ h) {
    int idx = blockIdx.x * blockDim.x + threadIdx.x;
    if (idx >= 8 * 513 * 200) return;
    int d = idx % 200;
    int n = (idx / 200) % 513;
    int b = idx / (200 * 513);
    float val;
    if (n == 0) {
        val = cls[d] + pos[d];
    } else {
        int p = n - 1;
        int t = d >> 3;
        int c = d & 7;
        val = conv[b * 102400 + c * 12800 + p * 25 + t];
        int ch = p >> 3, tw = p & 7;
        val += pos[(1 + ch) * 200 + d] + te[tw * 200 + d];
    }
    h[idx] = val;
}

// ---------------- weight convert+pad (vec4): fp32 [R][K] -> bf16 [R][KP] ----------------
__global__ void convpad_kernel(const float* __restrict__ src, short* __restrict__ dst,
                               int R, int K, int KP) {
    int idx = blockIdx.x * blockDim.x + threadIdx.x;
    int total = R * (KP >> 2);
    if (idx >= total) return;
    int r = idx / (KP >> 2);
    int c4 = (idx - r * (KP >> 2)) << 2;
    short4 o;
    if (c4 + 3 < K) {
        float4 f = *(const float4*)&src[(size_t)r * K + c4];
        o.x = f2bf(f.x); o.y = f2bf(f.y); o.z = f2bf(f.z); o.w = f2bf(f.w);
    } else {
        o.x = (c4 + 0 < K) ? f2bf(src[(size_t)r * K + c4 + 0]) : (short)0;
        o.y = (c4 + 1 < K) ? f2bf(src[(size_t)r * K + c4 + 1]) : (short)0;
        o.z = (c4 + 2 < K) ? f2bf(src[(size_t)r * K + c4 + 2]) : (short)0;
        o.w = (c4 + 3 < K) ? f2bf(src[(size_t)r * K + c4 + 3]) : (short)0;
    }
    *(short4*)&dst[(size_t)r * KP + c4] = o;
}

// ---------------- bias precompute via LDS table: 32-row chunks (2040 blocks) ----------
__global__ __launch_bounds__(256) void bias_lds_kernel(const float* __restrict__ table,
                                                       const int* __restrict__ ridx,
                                                       short* __restrict__ bias) {
    __shared__ float tl[1908];
    const int qt = blockIdx.x, hh = blockIdx.y, d = blockIdx.z;
    const float* tab = table + d * 19080;
    for (int i = threadIdx.x; i < 1908; i += 256) tl[i] = tab[i * 10 + hh];
    __syncthreads();
    const int q0 = qt * 32;
    const int nrows = min(32, 513 - q0);
    short* obase = bias + ((size_t)d * 10 + hh) * 513 * 576;
#pragma unroll 2
    for (int lin = threadIdx.x; lin < nrows * 144; lin += 256) {
        int r = lin / 144, j = lin % 144;
        int q = q0 + r;
        const int* rp = ridx + q * 513;
        int k0 = j * 4;
        float v[4];
#pragma unroll
        for (int e = 0; e < 4; e++) {
            int k = k0 + e;
            v[e] = (k < 513) ? tl[rp[k]] : 0.f;
        }
        uint2 pk;
        pk.x = pack2bf(v[0], v[1]);
        pk.y = pack2bf(v[2], v[3]);
        *(uint2*)&obase[(size_t)q * 576 + k0] = pk;
    }
}

// ---------------- LayerNorm over D=200; 4 rows per 256-thr block (one wave/row) ----------
__global__ __launch_bounds__(256) void ln_kernel(const float* __restrict__ in,
                                                 const float* __restrict__ g,
                                                 const float* __restrict__ b,
                                                 short* __restrict__ out) {
    int row = blockIdx.x * 4 + (threadIdx.x >> 6);
    int lane = threadIdx.x & 63;
    const float* x = in + (size_t)row * 200;
    float v[4];
    float s = 0.f;
#pragma unroll
    for (int i = 0; i < 4; i++) {
        int d = lane + i * 64;
        v[i] = (d < 200) ? x[d] : 0.f;
        s += v[i];
    }
#pragma unroll
    for (int o = 32; o; o >>= 1) s += __shfl_xor(s, o);
    float mean = s * (1.f / 200.f);
    float s2 = 0.f;
#pragma unroll
    for (int i = 0; i < 4; i++) {
        int d = lane + i * 64;
        float dv = (d < 200) ? (v[i] - mean) : 0.f;
        s2 += dv * dv;
    }
#pragma unroll
    for (int o = 32; o; o >>= 1) s2 += __shfl_xor(s2, o);
    float rstd = rsqrtf(s2 * (1.f / 200.f) + 1e-6f);
#pragma unroll
    for (int i = 0; i < 4; i++) {
        int d = lane + i * 64;
        float val = (d < 200) ? (v[i] - mean) * rstd * g[d] + b[d] : 0.f;
        out[(size_t)row * 256 + d] = f2bf(val);
    }
}

// ---------------- bf16 MFMA GEMM, double-buffered K-loop ----------------
// BM x BN block tile, BK=64, 4 waves 2x2. Counted vmcnt (never 0 mid-loop).
// EPI 1: Cf = res + gamma[n]*(acc+bias[n])
// EPI 2: Cb = bf16(gelu(acc+bias[n])), zero pad cols N..NPout
// EPI 3: qkv scatter -> Qb[b][h][576][32] (scaled), Kb same, Vt[b][h][32][576]
template <int EPI, int BM, int BN>
__global__ __launch_bounds__(256) void gemm_bf(const short* __restrict__ A,
                                               const short* __restrict__ W,
                                               float* __restrict__ Cf,
                                               short* __restrict__ Cb,
                                               const float* __restrict__ res,
                                               const float* __restrict__ bias,
                                               const float* __restrict__ gamma,
                                               int M, int N, int KP, int ldc, int NPout,
                                               short* __restrict__ Qb = nullptr,
                                               short* __restrict__ Kb = nullptr,
                                               short* __restrict__ Vt = nullptr) {
    constexpr int WM = BM / 2, WN = BN / 2;
    constexpr int AM = WM / 16, BNr = WN / 16;
    constexpr int LOADS = (BM + BN) / 32;   // gloads per thread per k-step
    __shared__ __align__(16) short Ss[2][(BM + BN) * 64];

    const int tid = threadIdx.x;
    const int w = tid >> 6, l = tid & 63;
    const int wm = (w >> 1) * WM, wn = (w & 1) * WN;
    const int bm = blockIdx.y * BM, bn = blockIdx.x * BN;

    f32x4 acc[AM][BNr] = {};

    auto stage = [&](int buf, int k0) {
#pragma unroll
        for (int it = 0; it < LOADS; it++) {
            int lin = it * 256 + tid;
            int row = lin >> 3, slot = lin & 7;
            int srcslot = slot ^ (row & 7);
            const short* g;
            if (it * 32 < BM) {
                g = A + (size_t)(bm + row) * KP + k0 + srcslot * 8;
            } else {
                g = W + (size_t)(bn + row - BM) * KP + k0 + srcslot * 8;
            }
            gload_lds16(g, (char*)Ss[buf] + lin * 16);
        }
    };

    const int nk = KP >> 6;
    stage(0, 0);
    int cur = 0;
    for (int kstep = 0; kstep < nk; kstep++) {
        if (kstep + 1 < nk) {
            stage(cur ^ 1, (kstep + 1) << 6);
            if constexpr (LOADS == 6) asm volatile("s_waitcnt vmcnt(6)" ::: "memory");
            else                      asm volatile("s_waitcnt vmcnt(4)" ::: "memory");
        } else {
            asm volatile("s_waitcnt vmcnt(0)" ::: "memory");
        }
        __builtin_amdgcn_s_barrier();

        const char* Sc = (const char*)Ss[cur];
#pragma unroll
        for (int kk = 0; kk < 2; kk++) {
            const int kbyte = kk * 64 + (l >> 4) * 16;
            bf16x8 af[AM], bfr[BNr];
#pragma unroll
            for (int i = 0; i < AM; i++) {
                int r = wm + i * 16 + (l & 15);
                af[i] = *(const bf16x8*)(Sc + r * 128 + (kbyte ^ ((r & 7) << 4)));
            }
#pragma unroll
            for (int j = 0; j < BNr; j++) {
                int r = BM + wn + j * 16 + (l & 15);
                bfr[j] = *(const bf16x8*)(Sc + r * 128 + (kbyte ^ ((r & 7) << 4)));
            }
#pragma unroll
            for (int i = 0; i < AM; i++)
#pragma unroll
                for (int j = 0; j < BNr; j++)
                    acc[i][j] = __builtin_amdgcn_mfma_f32_16x16x32_bf16(af[i], bfr[j], acc[i][j], 0, 0, 0);
        }
        __builtin_amdgcn_s_barrier();  // all waves done reading Ss[cur] before overwrite
        cur ^= 1;
    }

    const int col0 = bn + wn + (l & 15);
    const int rbase = (l >> 4) * 4;
#pragma unroll
    for (int i = 0; i < AM; i++) {
#pragma unroll
        for (int r = 0; r < 4; r++) {
            int gm = bm + wm + i * 16 + rbase + r;
            if (gm >= M) continue;
#pragma unroll
            for (int j = 0; j < BNr; j++) {
                int gn = col0 + j * 16;
                float v = acc[i][j][r];
                if (EPI == 1) {
                    if (gn < N) Cf[(size_t)gm * ldc + gn] =
                        res[(size_t)gm * ldc + gn] + gamma[gn] * (v + bias[gn]);
                } else if (EPI == 2) {
                    if (gn < NPout)
                        Cb[(size_t)gm * ldc + gn] = (gn < N) ? f2bf(gelu_exact(v + bias[gn])) : (short)0;
                } else {  // EPI 3: qkv scatter
                    if (gn < 600) {
                        int bb2 = gm / 513, n = gm - bb2 * 513;
                        if (gn < 200) {
                            int hq = gn / 20, dq = gn - hq * 20;
                            Qb[((size_t)(bb2 * 10 + hq) * 576 + n) * 32 + dq] =
                                f2bf(v * 0.22360679774997896f);
                        } else if (gn < 400) {
                            int gk = gn - 200, hk = gk / 20, dk = gk - hk * 20;
                            Kb[((size_t)(bb2 * 10 + hk) * 576 + n) * 32 + dk] = f2bf(v);
                        } else {
                            int gv = gn - 400, hv = gv / 20, dv2 = gv - hv * 20;
                            Vt[((size_t)(bb2 * 10 + hv) * 32 + dv2) * 576 + n] = f2bf(v);
                        }
                    }
                }
            }
        }
    }
}

// ---------------- MFMA flash attention: dbuf K/V staging, bias direct-to-register -------
__global__ __launch_bounds__(256) void attn_mfma2(const short* __restrict__ Qb,
                                                  const short* __restrict__ Kb,
                                                  const short* __restrict__ Vt,
                                                  const short* __restrict__ biasb,
                                                  short* __restrict__ ob) {
    __shared__ __align__(16) short Klds[2][64 * 32];
    __shared__ __align__(16) short Vlds[2][32 * 64];
    __shared__ __align__(16) short Pl[4 * 16 * 72];

    const int orig = blockIdx.x;
    const int wg = (orig & 7) * 90 + (orig >> 3);   // XCD-chunked bijection (720 = 8*90)
    const int hh = wg / 72;
    const int rem = wg % 72;
    const int qt = rem >> 3, b = rem & 7;

    const int t = threadIdx.x, wave = t >> 6, l = t & 63;
    const int lq = l & 15, hi = l >> 4;
    const int n = qt * 64 + wave * 16 + lq;
    const int nc = min(n, 512);

    const size_t bh = (size_t)(b * 10 + hh);
    const short* Kbase = Kb + bh * 576 * 32;
    const short* Vbase = Vt + bh * 32 * 576;
    const short* Brow  = biasb + ((size_t)hh * 513 + nc) * 576;

    bf16x8 qf = *(const bf16x8*)&Qb[(bh * 576 + nc) * 32 + hi * 8];

    const int krow = t >> 2, kch = t & 3;
    const short* ksrc = Kbase + (size_t)krow * 32 + (kch ^ ((krow >> 2) & 3)) * 8;
    const int vrow = t >> 3, vch = t & 7;
    const short* vsrc = Vbase + (size_t)vrow * 576 + (vch ^ (vrow & 7)) * 8;

    float mrun = -1e30f, lsum = 0.f;
    f32x4 oacc0 = {}, oacc1 = {};
    const f32x4 zero4 = {};

    gload_lds16(ksrc, (char*)Klds[0] + t * 16);
    gload_lds16(vsrc, (char*)Vlds[0] + t * 16);

    int cur = 0;
    for (int kt = 0; kt < 9; kt++) {
        const int koff = kt * 64;

        uint2 bl[4];
#pragma unroll
        for (int c = 0; c < 4; c++)
            bl[c] = *(const uint2*)&Brow[koff + c * 16 + hi * 4];

        if (kt < 8) {
            const int knext = koff + 64;
            gload_lds16(ksrc + (size_t)knext * 32, (char*)Klds[cur ^ 1] + t * 16);
            gload_lds16(vsrc + knext, (char*)Vlds[cur ^ 1] + t * 16);
            asm volatile("s_waitcnt vmcnt(2)" ::: "memory");
        } else {
            asm volatile("s_waitcnt vmcnt(0)" ::: "memory");
        }
        __builtin_amdgcn_s_barrier();

        const short* Kc = Klds[cur];
        const short* Vc = Vlds[cur];

        f32x4 s[4];
        __builtin_amdgcn_s_setprio(1);
#pragma unroll
        for (int c = 0; c < 4; c++) {
            int r = c * 16 + lq;
            bf16x8 kf = *(const bf16x8*)((const char*)Kc + r * 64 + ((hi ^ ((lq >> 2) & 3)) << 4));
            s[c] = __builtin_amdgcn_mfma_f32_16x16x32_bf16(kf, qf, zero4, 0, 0, 0);
        }
        __builtin_amdgcn_s_setprio(0);

        float sv[4][4];
        float tm = -1e30f;
#pragma unroll
        for (int c = 0; c < 4; c++) {
            float bv[4] = { bf2f((unsigned short)(bl[c].x & 0xFFFF)), bf2f((unsigned short)(bl[c].x >> 16)),
                            bf2f((unsigned short)(bl[c].y & 0xFFFF)), bf2f((unsigned short)(bl[c].y >> 16)) };
            int kglob = koff + c * 16 + hi * 4;
#pragma unroll
            for (int r = 0; r < 4; r++) {
                float val = s[c][r] + bv[r];
                if (kglob + r > 512) val = -1e30f;
                sv[c][r] = val;
                tm = fmaxf(tm, val);
            }
        }
        tm = fmaxf(tm, __shfl_xor(tm, 16));
        tm = fmaxf(tm, __shfl_xor(tm, 32));
        float mnew = fmaxf(mrun, tm);
        float resc = __expf(mrun - mnew);
        mrun = mnew;

        float ts = 0.f;
#pragma unroll
        for (int c = 0; c < 4; c++) {
            float p0 = __expf(sv[c][0] - mnew);
            float p1 = __expf(sv[c][1] - mnew);
            float p2 = __expf(sv[c][2] - mnew);
            float p3 = __expf(sv[c][3] - mnew);
            ts += (p0 + p1) + (p2 + p3);
            uint2 pk;
            pk.x = pack2bf(p0, p1);
            pk.y = pack2bf(p2, p3);
            *(uint2*)&Pl[wave * 1152 + lq * 72 + c * 16 + hi * 4] = pk;
        }
        ts += __shfl_xor(ts, 16);
        ts += __shfl_xor(ts, 32);
        lsum = lsum * resc + ts;
        oacc0 *= resc;
        oacc1 *= resc;

        __builtin_amdgcn_s_setprio(1);
#pragma unroll
        for (int kc = 0; kc < 2; kc++) {
            bf16x8 pf = *(const bf16x8*)&Pl[wave * 1152 + lq * 72 + kc * 32 + hi * 8];
            bf16x8 vf0 = *(const bf16x8*)((const char*)Vc + lq * 128 +
                                          (((kc * 4 + hi) ^ (lq & 7)) << 4));
            bf16x8 vf1 = *(const bf16x8*)((const char*)Vc + (16 + lq) * 128 +
                                          (((kc * 4 + hi) ^ (lq & 7)) << 4));
            oacc0 = __builtin_amdgcn_mfma_f32_16x16x32_bf16(vf0, pf, oacc0, 0, 0, 0);
            oacc1 = __builtin_amdgcn_mfma_f32_16x16x32_bf16(vf1, pf, oacc1, 0, 0, 0);
        }
        __builtin_amdgcn_s_setprio(0);

        __builtin_amdgcn_s_barrier();
        cur ^= 1;
    }

    if (n < 513) {
        float inv = 1.f / lsum;
        short* op = ob + (size_t)(b * 513 + n) * 256 + hh * 20;
        {
            uint2 pk;
            pk.x = pack2bf(oacc0[0] * inv, oacc0[1] * inv);
            pk.y = pack2bf(oacc0[2] * inv, oacc0[3] * inv);
            *(uint2*)&op[hi * 4] = pk;
        }
        if (hi == 0) {
            uint2 pk;
            pk.x = pack2bf(oacc1[0] * inv, oacc1[1] * inv);
            pk.y = pack2bf(oacc1[2] * inv, oacc1[3] * inv);
            *(uint2*)&op[16] = pk;
        }
    }
}

// ---------------- final: mean-pool patches -> LN -> head (200 -> 4) ----------------
__global__ __launch_bounds__(256) void final_kernel(const float* __restrict__ h,
                                                    const float* __restrict__ g,
                                                    const float* __restrict__ bb,
                                                    const float* __restrict__ hw,
                                                    const float* __restrict__ hb,
                                                    float* __restrict__ out) {
    __shared__ float pool[256];
    __shared__ float red[256];
    int b = blockIdx.x, t = threadIdx.x;
    float s = 0.f;
    if (t < 200) {
        const float* hp = h + b * 513 * 200 + 200 + t;
        for (int p = 0; p < 512; p++) s += hp[p * 200];
        s *= (1.f / 512.f);
    }
    pool[t] = (t < 200) ? s : 0.f;
    red[t] = pool[t];
    __syncthreads();
    for (int o = 128; o; o >>= 1) {
        if (t < o) red[t] += red[t + o];
        __syncthreads();
    }
    float mean = red[0] / 200.f;
    __syncthreads();
    float dv = (t < 200) ? (pool[t] - mean) : 0.f;
    red[t] = dv * dv;
    __syncthreads();
    for (int o = 128; o; o >>= 1) {
        if (t < o) red[t] += red[t + o];
        __syncthreads();
    }
    float var = red[0] / 200.f;
    float rstd = rsqrtf(var + 1e-6f);
    __syncthreads();
    if (t < 200) pool[t] = (pool[t] - mean) * rstd * g[t] + bb[t];
    __syncthreads();
    if (t < 4) {
        float acc = hb[t];
        for (int d2 = 0; d2 < 200; d2++) acc += pool[d2] * hw[t * 200 + d2];
        out[b * 4 + t] = acc;
    }
}

extern "C" void kernel_launch(void* const* d_in, const int* in_sizes, int n_in,
                              void* d_out, int out_size, void* d_ws, size_t ws_size,
                              hipStream_t stream) {
    const float* x        = (const float*)d_in[0];
    const float* conv1_w  = (const float*)d_in[1];
    const float* conv1_b  = (const float*)d_in[2];
    const float* gn1_g    = (const float*)d_in[3];
    const float* gn1_b    = (const float*)d_in[4];
    const float* conv2_w  = (const float*)d_in[5];
    const float* conv2_b  = (const float*)d_in[6];
    const float* gn2_g    = (const float*)d_in[7];
    const float* gn2_b    = (const float*)d_in[8];
    const float* conv3_w  = (const float*)d_in[9];
    const float* conv3_b  = (const float*)d_in[10];
    const float* gn3_g    = (const float*)d_in[11];
    const float* gn3_b    = (const float*)d_in[12];
    const float* cls_tok  = (const float*)d_in[13];
    const float* pos_emb  = (const float*)d_in[14];
    const float* time_emb = (const float*)d_in[15];
    const float* ln1_g    = (const float*)d_in[16];
    const float* ln1_b    = (const float*)d_in[17];
    const float* qkv_w    = (const float*)d_in[18];
    const float* rel_tab  = (const float*)d_in[19];
    const float* proj_w   = (const float*)d_in[20];
    const float* proj_b   = (const float*)d_in[21];
    const float* gamma1   = (const float*)d_in[22];
    const float* ln2_g    = (const float*)d_in[23];
    const float* ln2_b    = (const float*)d_in[24];
    const float* fc1_w    = (const float*)d_in[25];
    const float* fc1_b    = (const float*)d_in[26];
    const float* fc2_w    = (const float*)d_in[27];
    const float* fc2_b    = (const float*)d_in[28];
    const float* gamma2   = (const float*)d_in[29];
    const float* fcn_g    = (const float*)d_in[30];
    const float* fcn_b    = (const float*)d_in[31];
    const float* head_w   = (const float*)d_in[32];
    const float* head_b   = (const float*)d_in[33];
    const int*   rel_idx  = (const int*)d_in[34];

    // ---- workspace layout (bytes), total ~102 MB ----
    char* p = (char*)d_ws;
    float* h    = (float*)p; p += 3283200;          // 8*513*200 f32
    char* qreg = p;                                  // multi-phase region
    float* c1   = (float*)qreg;
    float* c2   = c1 + 819200;
    short* Qb   = (short*)qreg;                     // [8][10][576][32]
    short* Kb   = Qb + 1474560;
    short* Vt   = Kb + 1474560;                     // [8][10][32][576]
    short* mlp  = (short*)qreg;                     // [4104][832] (MLP phase)
    p += 9849600;
    short* y    = (short*)p; p += 2101248;          // 4104*256 bf16
    short* ob   = (short*)p; p += 2101248;          // 4104*256 bf16
    short* wqkv = (short*)p; p += 3686400;
    short* wproj= (short*)p; p += 1228800;
    short* wfc1 = (short*)p; p += 4915200;
    short* wfc2 = (short*)p; p += 3993600;
    short* biasb= (short*)p; p += 12 * 5909760;     // [12][10][513][576] bf16 = 70.9 MB
    float* stats= (float*)p;

    // ---- upfront precompute ----
    convpad_kernel<<<(7200 * 64 + 255) / 256, 256, 0, stream>>>(qkv_w, wqkv, 7200, 200, 256);
    convpad_kernel<<<(2400 * 64 + 255) / 256, 256, 0, stream>>>(proj_w, wproj, 2400, 200, 256);
    convpad_kernel<<<(9600 * 64 + 255) / 256, 256, 0, stream>>>(fc1_w, wfc1, 9600, 200, 256);
    convpad_kernel<<<(2400 * 208 + 255) / 256, 256, 0, stream>>>(fc2_w, wfc2, 2400, 800, 832);
    bias_lds_kernel<<<dim3(17, 10, 12), 256, 0, stream>>>(rel_tab, rel_idx, biasb);
    hipMemsetAsync(ob, 0, 2101248, stream);

    // ---- patch embed ----
    conv1_kernel<<<3200, 256, 0, stream>>>(x, conv1_w, conv1_b, c1);
    gn_stats_kernel<<<32, 256, 0, stream>>>(c1, stats);
    gn_apply_kernel<<<3200, 256, 0, stream>>>(c1, stats, gn1_g, gn1_b);
    conv3x1_kernel<<<3200, 256, 0, stream>>>(c1, conv2_w, conv2_b, c2);
    gn_stats_kernel<<<32, 256, 0, stream>>>(c2, stats);
    gn_apply_kernel<<<3200, 256, 0, stream>>>(c2, stats, gn2_g, gn2_b);
    conv3x1_kernel<<<3200, 256, 0, stream>>>(c2, conv3_w, conv3_b, c1);
    gn_stats_kernel<<<32, 256, 0, stream>>>(c1, stats);
    gn_apply_kernel<<<3200, 256, 0, stream>>>(c1, stats, gn3_g, gn3_b);
    embed_kernel<<<(820800 + 255) / 256, 256, 0, stream>>>(c1, cls_tok, pos_emb, time_emb, h);

    hipMemsetAsync(Qb, 0, 3 * 1474560 * 2, stream);  // zero QKV pad regions (post conv phase)

    // ---- transformer layers ----
    for (int d = 0; d < 12; d++) {
        ln_kernel<<<1026, 256, 0, stream>>>(h, ln1_g + d * 200, ln1_b + d * 200, y);
        gemm_bf<3, 64, 64><<<dim3(10, 65), 256, 0, stream>>>(y, wqkv + d * 153600,
                                                             nullptr, nullptr, nullptr, nullptr, nullptr,
                                                             4104, 600, 256, 0, 0, Qb, Kb, Vt);
        attn_mfma2<<<720, 256, 0, stream>>>(Qb, Kb, Vt, biasb + (size_t)d * 2954880, ob);
        gemm_bf<1, 64, 64><<<dim3(4, 65), 256, 0, stream>>>(ob, wproj + d * 51200, h, nullptr,
                                                            h, proj_b + d * 200, gamma1 + d * 200,
                                                            4104, 200, 256, 200, 0);
        ln_kernel<<<1026, 256, 0, stream>>>(h, ln2_g + d * 200, ln2_b + d * 200, y);
        gemm_bf<2, 64, 64><<<dim3(13, 65), 256, 0, stream>>>(y, wfc1 + d * 204800, nullptr, mlp,
                                                             nullptr, fc1_b + d * 800, nullptr,
                                                             4104, 800, 256, 832, 832);
        gemm_bf<1, 64, 64><<<dim3(4, 65), 256, 0, stream>>>(mlp, wfc2 + d * 166400, h, nullptr,
                                                            h, fc2_b + d * 200, gamma2 + d * 200,
                                                            4104, 200, 832, 200, 0);
    }

    // ---- pool + head ----
    final_kernel<<<8, 256, 0, stream>>>(h, fcn_g, fcn_b, head_w, head_b, (float*)d_out);
}

// Round 15
// 982.228 us; speedup vs baseline: 1.1196x; 1.0559x over previous
//
#include <hip/hip_runtime.h>
#include <math.h>

#define DEV static __device__ __forceinline__

typedef __attribute__((ext_vector_type(8))) short bf16x8;
typedef __attribute__((ext_vector_type(4))) float f32x4;

DEV float gelu_exact(float x) {
    return 0.5f * x * (1.0f + erff(x * 0.70710678118654752f));
}

DEV short f2bf(float f) {
    union { float f; unsigned u; } v; v.f = f;
    unsigned r = v.u + 0x7FFF + ((v.u >> 16) & 1);  // round-to-nearest-even
    return (short)(r >> 16);
}

DEV float bf2f(unsigned short b) {
    union { unsigned u; float f; } v; v.u = ((unsigned)b) << 16;
    return v.f;
}

DEV unsigned pack2bf(float a, float b) {
    return ((unsigned)(unsigned short)f2bf(a)) | (((unsigned)(unsigned short)f2bf(b)) << 16);
}

DEV void gload_lds16(const void* g, void* lds) {
    __builtin_amdgcn_global_load_lds(
        (const __attribute__((address_space(1))) void*)g,
        (__attribute__((address_space(3))) void*)lds, 16, 0, 0);
}

// ---------------- conv1: (B,1,512,200) -> (B,8,512,25), k=15 stride=8 pad=7 ----------------
__global__ void conv1_kernel(const float* __restrict__ x, const float* __restrict__ w,
                             const float* __restrict__ bias, float* __restrict__ out) {
    int idx = blockIdx.x * blockDim.x + threadIdx.x;
    const int total = 8 * 8 * 512 * 25;
    if (idx >= total) return;
    int ow = idx % 25;
    int p  = (idx / 25) % 512;
    int oc = (idx / (25 * 512)) % 8;
    int b  = idx / (25 * 512 * 8);
    const float* xp = x + b * 512 * 200 + p * 200;
    const float* wp = w + oc * 15;
    float acc = bias[oc];
    int t0 = ow * 8 - 7;
#pragma unroll
    for (int k = 0; k < 15; k++) {
        int t = t0 + k;
        if (t >= 0 && t < 200) acc += wp[k] * xp[t];
    }
    out[idx] = acc;
}

// ---------------- conv 1x3 (pad 1) on (B,8,512,25) ----------------
__global__ void conv3x1_kernel(const float* __restrict__ in, const float* __restrict__ w,
                               const float* __restrict__ bias, float* __restrict__ out) {
    int idx = blockIdx.x * blockDim.x + threadIdx.x;
    const int total = 8 * 8 * 512 * 25;
    if (idx >= total) return;
    int ow = idx % 25;
    int p  = (idx / 25) % 512;
    int oc = (idx / 12800) & 7;
    int b  = idx / 102400;
    float acc = bias[oc];
#pragma unroll
    for (int ic = 0; ic < 8; ic++) {
        const float* ip = in + b * 102400 + ic * 12800 + p * 25;
        const float* wp = w + oc * 24 + ic * 3;
        if (ow > 0)  acc += wp[0] * ip[ow - 1];
        acc += wp[1] * ip[ow];
        if (ow < 24) acc += wp[2] * ip[ow + 1];
    }
    out[idx] = acc;
}

// ---------------- groupnorm ----------------
__global__ void gn_stats_kernel(const float* __restrict__ buf, float* __restrict__ stats) {
    int b = blockIdx.x >> 2, g = blockIdx.x & 3;
    const float* base = buf + b * 102400 + g * 2 * 12800;
    float s = 0.f, s2 = 0.f;
    for (int l = threadIdx.x; l < 25600; l += 256) {
        float v = base[l];
        s += v; s2 += v * v;
    }
    __shared__ float ss[256], ss2[256];
    ss[threadIdx.x] = s; ss2[threadIdx.x] = s2;
    __syncthreads();
    for (int o = 128; o; o >>= 1) {
        if (threadIdx.x < o) { ss[threadIdx.x] += ss[threadIdx.x + o]; ss2[threadIdx.x] += ss2[threadIdx.x + o]; }
        __syncthreads();
    }
    if (threadIdx.x == 0) {
        float m = ss[0] / 25600.f;
        float v = ss2[0] / 25600.f - m * m;
        stats[blockIdx.x * 2] = m;
        stats[blockIdx.x * 2 + 1] = v;
    }
}

__global__ void gn_apply_kernel(float* __restrict__ buf, const float* __restrict__ stats,
                                const float* __restrict__ g, const float* __restrict__ bb) {
    int idx = blockIdx.x * blockDim.x + threadIdx.x;
    if (idx >= 8 * 102400) return;
    int c = (idx / 12800) & 7;
    int b = idx / 102400;
    int grp = c >> 1;
    float m = stats[(b * 4 + grp) * 2];
    float v = stats[(b * 4 + grp) * 2 + 1];
    float val = (buf[idx] - m) * rsqrtf(v + 1e-5f) * g[c] + bb[c];
    buf[idx] = gelu_exact(val);
}

// ---------------- embed ----------------
__global__ void embed_kernel(const float* __restrict__ conv, const float* __restrict__ cls,
                             const float* __restrict__ pos, const float* __restrict__ te,
                             float* __restrict__ h) {
    int idx = blockIdx.x * blockDim.x + threadIdx.x;
    if (idx >= 8 * 513 * 200) return;
    int d = idx % 200;
    int n = (idx / 200) % 513;
    int b = idx / (200 * 513);
    float val;
    if (n == 0) {
        val = cls[d] + pos[d];
    } else {
        int p = n - 1;
        int t = d >> 3;
        int c = d & 7;
        val = conv[b * 102400 + c * 12800 + p * 25 + t];
        int ch = p >> 3, tw = p & 7;
        val += pos[(1 + ch) * 200 + d] + te[tw * 200 + d];
    }
    h[idx] = val;
}

// ---------------- weight convert+pad (vec4): fp32 [R][K] -> bf16 [R][KP] ----------------
__global__ void convpad_kernel(const float* __restrict__ src, short* __restrict__ dst,
                               int R, int K, int KP) {
    int idx = blockIdx.x * blockDim.x + threadIdx.x;
    int total = R * (KP >> 2);
    if (idx >= total) return;
    int r = idx / (KP >> 2);
    int c4 = (idx - r * (KP >> 2)) << 2;
    short4 o;
    if (c4 + 3 < K) {
        float4 f = *(const float4*)&src[(size_t)r * K + c4];
        o.x = f2bf(f.x); o.y = f2bf(f.y); o.z = f2bf(f.z); o.w = f2bf(f.w);
    } else {
        o.x = (c4 + 0 < K) ? f2bf(src[(size_t)r * K + c4 + 0]) : (short)0;
        o.y = (c4 + 1 < K) ? f2bf(src[(size_t)r * K + c4 + 1]) : (short)0;
        o.z = (c4 + 2 < K) ? f2bf(src[(size_t)r * K + c4 + 2]) : (short)0;
        o.w = (c4 + 3 < K) ? f2bf(src[(size_t)r * K + c4 + 3]) : (short)0;
    }
    *(short4*)&dst[(size_t)r * KP + c4] = o;
}

// ---------------- bias precompute via LDS table: 32-row chunks (2040 blocks) ----------
__global__ __launch_bounds__(256) void bias_lds_kernel(const float* __restrict__ table,
                                                       const int* __restrict__ ridx,
                                                       short* __restrict__ bias) {
    __shared__ float tl[1908];
    const int qt = blockIdx.x, hh = blockIdx.y, d = blockIdx.z;
    const float* tab = table + d * 19080;
    for (int i = threadIdx.x; i < 1908; i += 256) tl[i] = tab[i * 10 + hh];
    __syncthreads();
    const int q0 = qt * 32;
    const int nrows = min(32, 513 - q0);
    short* obase = bias + ((size_t)d * 10 + hh) * 513 * 576;
#pragma unroll 2
    for (int lin = threadIdx.x; lin < nrows * 144; lin += 256) {
        int r = lin / 144, j = lin % 144;
        int q = q0 + r;
        const int* rp = ridx + q * 513;
        int k0 = j * 4;
        float v[4];
#pragma unroll
        for (int e = 0; e < 4; e++) {
            int k = k0 + e;
            v[e] = (k < 513) ? tl[rp[k]] : 0.f;
        }
        uint2 pk;
        pk.x = pack2bf(v[0], v[1]);
        pk.y = pack2bf(v[2], v[3]);
        *(uint2*)&obase[(size_t)q * 576 + k0] = pk;
    }
}

// ---------------- LayerNorm over D=200; 4 rows per 256-thr block (one wave/row) ----------
__global__ __launch_bounds__(256) void ln_kernel(const float* __restrict__ in,
                                                 const float* __restrict__ g,
                                                 const float* __restrict__ b,
                                                 short* __restrict__ out) {
    int row = blockIdx.x * 4 + (threadIdx.x >> 6);
    int lane = threadIdx.x & 63;
    const float* x = in + (size_t)row * 200;
    float v[4];
    float s = 0.f;
#pragma unroll
    for (int i = 0; i < 4; i++) {
        int d = lane + i * 64;
        v[i] = (d < 200) ? x[d] : 0.f;
        s += v[i];
    }
#pragma unroll
    for (int o = 32; o; o >>= 1) s += __shfl_xor(s, o);
    float mean = s * (1.f / 200.f);
    float s2 = 0.f;
#pragma unroll
    for (int i = 0; i < 4; i++) {
        int d = lane + i * 64;
        float dv = (d < 200) ? (v[i] - mean) : 0.f;
        s2 += dv * dv;
    }
#pragma unroll
    for (int o = 32; o; o >>= 1) s2 += __shfl_xor(s2, o);
    float rstd = rsqrtf(s2 * (1.f / 200.f) + 1e-6f);
#pragma unroll
    for (int i = 0; i < 4; i++) {
        int d = lane + i * 64;
        float val = (d < 200) ? (v[i] - mean) * rstd * g[d] + b[d] : 0.f;
        out[(size_t)row * 256 + d] = f2bf(val);
    }
}

// ---------------- bf16 MFMA GEMM, double-buffered K-loop ----------------
// BM x BN block tile, BK=64, 4 waves 2x2. Counted vmcnt (never 0 mid-loop).
// BM=32 everywhere this round: latency-bound blocks, 2x grid -> TLP covers the stalls.
// EPI 1: Cf = res + gamma[n]*(acc+bias[n])
// EPI 2: Cb = bf16(gelu(acc+bias[n])), zero pad cols N..NPout
// EPI 3: qkv scatter -> Qb[b][h][576][32] (scaled), Kb same, Vt[b][h][32][576]
template <int EPI, int BM, int BN>
__global__ __launch_bounds__(256) void gemm_bf(const short* __restrict__ A,
                                               const short* __restrict__ W,
                                               float* __restrict__ Cf,
                                               short* __restrict__ Cb,
                                               const float* __restrict__ res,
                                               const float* __restrict__ bias,
                                               const float* __restrict__ gamma,
                                               int M, int N, int KP, int ldc, int NPout,
                                               short* __restrict__ Qb = nullptr,
                                               short* __restrict__ Kb = nullptr,
                                               short* __restrict__ Vt = nullptr) {
    constexpr int WM = BM / 2, WN = BN / 2;
    constexpr int AM = WM / 16, BNr = WN / 16;
    constexpr int LOADS = (BM + BN) / 32;   // gloads per thread per k-step
    __shared__ __align__(16) short Ss[2][(BM + BN) * 64];

    const int tid = threadIdx.x;
    const int w = tid >> 6, l = tid & 63;
    const int wm = (w >> 1) * WM, wn = (w & 1) * WN;
    const int bm = blockIdx.y * BM, bn = blockIdx.x * BN;

    f32x4 acc[AM][BNr] = {};

    auto stage = [&](int buf, int k0) {
#pragma unroll
        for (int it = 0; it < LOADS; it++) {
            int lin = it * 256 + tid;
            int row = lin >> 3, slot = lin & 7;
            int srcslot = slot ^ (row & 7);
            const short* g;
            if (it * 32 < BM) {
                g = A + (size_t)(bm + row) * KP + k0 + srcslot * 8;
            } else {
                g = W + (size_t)(bn + row - BM) * KP + k0 + srcslot * 8;
            }
            gload_lds16(g, (char*)Ss[buf] + lin * 16);
        }
    };

    const int nk = KP >> 6;
    stage(0, 0);
    int cur = 0;
    for (int kstep = 0; kstep < nk; kstep++) {
        if (kstep + 1 < nk) {
            stage(cur ^ 1, (kstep + 1) << 6);
            if constexpr (LOADS == 6)      asm volatile("s_waitcnt vmcnt(6)" ::: "memory");
            else if constexpr (LOADS == 4) asm volatile("s_waitcnt vmcnt(4)" ::: "memory");
            else                           asm volatile("s_waitcnt vmcnt(3)" ::: "memory");
        } else {
            asm volatile("s_waitcnt vmcnt(0)" ::: "memory");
        }
        __builtin_amdgcn_s_barrier();

        const char* Sc = (const char*)Ss[cur];
#pragma unroll
        for (int kk = 0; kk < 2; kk++) {
            const int kbyte = kk * 64 + (l >> 4) * 16;
            bf16x8 af[AM], bfr[BNr];
#pragma unroll
            for (int i = 0; i < AM; i++) {
                int r = wm + i * 16 + (l & 15);
                af[i] = *(const bf16x8*)(Sc + r * 128 + (kbyte ^ ((r & 7) << 4)));
            }
#pragma unroll
            for (int j = 0; j < BNr; j++) {
                int r = BM + wn + j * 16 + (l & 15);
                bfr[j] = *(const bf16x8*)(Sc + r * 128 + (kbyte ^ ((r & 7) << 4)));
            }
#pragma unroll
            for (int i = 0; i < AM; i++)
#pragma unroll
                for (int j = 0; j < BNr; j++)
                    acc[i][j] = __builtin_amdgcn_mfma_f32_16x16x32_bf16(af[i], bfr[j], acc[i][j], 0, 0, 0);
        }
        __builtin_amdgcn_s_barrier();  // all waves done reading Ss[cur] before overwrite
        cur ^= 1;
    }

    const int col0 = bn + wn + (l & 15);
    const int rbase = (l >> 4) * 4;
#pragma unroll
    for (int i = 0; i < AM; i++) {
#pragma unroll
        for (int r = 0; r < 4; r++) {
            int gm = bm + wm + i * 16 + rbase + r;
            if (gm >= M) continue;
#pragma unroll
            for (int j = 0; j < BNr; j++) {
                int gn = col0 + j * 16;
                float v = acc[i][j][r];
                if (EPI == 1) {
                    if (gn < N) Cf[(size_t)gm * ldc + gn] =
                        res[(size_t)gm * ldc + gn] + gamma[gn] * (v + bias[gn]);
                } else if (EPI == 2) {
                    if (gn < NPout)
                        Cb[(size_t)gm * ldc + gn] = (gn < N) ? f2bf(gelu_exact(v + bias[gn])) : (short)0;
                } else {  // EPI 3: qkv scatter
                    if (gn < 600) {
                        int bb2 = gm / 513, n = gm - bb2 * 513;
                        if (gn < 200) {
                            int hq = gn / 20, dq = gn - hq * 20;
                            Qb[((size_t)(bb2 * 10 + hq) * 576 + n) * 32 + dq] =
                                f2bf(v * 0.22360679774997896f);
                        } else if (gn < 400) {
                            int gk = gn - 200, hk = gk / 20, dk = gk - hk * 20;
                            Kb[((size_t)(bb2 * 10 + hk) * 576 + n) * 32 + dk] = f2bf(v);
                        } else {
                            int gv = gn - 400, hv = gv / 20, dv2 = gv - hv * 20;
                            Vt[((size_t)(bb2 * 10 + hv) * 32 + dv2) * 576 + n] = f2bf(v);
                        }
                    }
                }
            }
        }
    }
}

// ---------------- MFMA flash attention: dbuf K/V staging, bias direct-to-register -------
__global__ __launch_bounds__(256) void attn_mfma2(const short* __restrict__ Qb,
                                                  const short* __restrict__ Kb,
                                                  const short* __restrict__ Vt,
                                                  const short* __restrict__ biasb,
                                                  short* __restrict__ ob) {
    __shared__ __align__(16) short Klds[2][64 * 32];
    __shared__ __align__(16) short Vlds[2][32 * 64];
    __shared__ __align__(16) short Pl[4 * 16 * 72];

    const int orig = blockIdx.x;
    const int wg = (orig & 7) * 90 + (orig >> 3);   // XCD-chunked bijection (720 = 8*90)
    const int hh = wg / 72;
    const int rem = wg % 72;
    const int qt = rem >> 3, b = rem & 7;

    const int t = threadIdx.x, wave = t >> 6, l = t & 63;
    const int lq = l & 15, hi = l >> 4;
    const int n = qt * 64 + wave * 16 + lq;
    const int nc = min(n, 512);

    const size_t bh = (size_t)(b * 10 + hh);
    const short* Kbase = Kb + bh * 576 * 32;
    const short* Vbase = Vt + bh * 32 * 576;
    const short* Brow  = biasb + ((size_t)hh * 513 + nc) * 576;

    bf16x8 qf = *(const bf16x8*)&Qb[(bh * 576 + nc) * 32 + hi * 8];

    const int krow = t >> 2, kch = t & 3;
    const short* ksrc = Kbase + (size_t)krow * 32 + (kch ^ ((krow >> 2) & 3)) * 8;
    const int vrow = t >> 3, vch = t & 7;
    const short* vsrc = Vbase + (size_t)vrow * 576 + (vch ^ (vrow & 7)) * 8;

    float mrun = -1e30f, lsum = 0.f;
    f32x4 oacc0 = {}, oacc1 = {};
    const f32x4 zero4 = {};

    gload_lds16(ksrc, (char*)Klds[0] + t * 16);
    gload_lds16(vsrc, (char*)Vlds[0] + t * 16);

    int cur = 0;
    for (int kt = 0; kt < 9; kt++) {
        const int koff = kt * 64;

        uint2 bl[4];
#pragma unroll
        for (int c = 0; c < 4; c++)
            bl[c] = *(const uint2*)&Brow[koff + c * 16 + hi * 4];

        if (kt < 8) {
            const int knext = koff + 64;
            gload_lds16(ksrc + (size_t)knext * 32, (char*)Klds[cur ^ 1] + t * 16);
            gload_lds16(vsrc + knext, (char*)Vlds[cur ^ 1] + t * 16);
            asm volatile("s_waitcnt vmcnt(2)" ::: "memory");
        } else {
            asm volatile("s_waitcnt vmcnt(0)" ::: "memory");
        }
        __builtin_amdgcn_s_barrier();

        const short* Kc = Klds[cur];
        const short* Vc = Vlds[cur];

        f32x4 s[4];
        __builtin_amdgcn_s_setprio(1);
#pragma unroll
        for (int c = 0; c < 4; c++) {
            int r = c * 16 + lq;
            bf16x8 kf = *(const bf16x8*)((const char*)Kc + r * 64 + ((hi ^ ((lq >> 2) & 3)) << 4));
            s[c] = __builtin_amdgcn_mfma_f32_16x16x32_bf16(kf, qf, zero4, 0, 0, 0);
        }
        __builtin_amdgcn_s_setprio(0);

        float sv[4][4];
        float tm = -1e30f;
#pragma unroll
        for (int c = 0; c < 4; c++) {
            float bv[4] = { bf2f((unsigned short)(bl[c].x & 0xFFFF)), bf2f((unsigned short)(bl[c].x >> 16)),
                            bf2f((unsigned short)(bl[c].y & 0xFFFF)), bf2f((unsigned short)(bl[c].y >> 16)) };
            int kglob = koff + c * 16 + hi * 4;
#pragma unroll
            for (int r = 0; r < 4; r++) {
                float val = s[c][r] + bv[r];
                if (kglob + r > 512) val = -1e30f;
                sv[c][r] = val;
                tm = fmaxf(tm, val);
            }
        }
        tm = fmaxf(tm, __shfl_xor(tm, 16));
        tm = fmaxf(tm, __shfl_xor(tm, 32));
        float mnew = fmaxf(mrun, tm);
        float resc = __expf(mrun - mnew);
        mrun = mnew;

        float ts = 0.f;
#pragma unroll
        for (int c = 0; c < 4; c++) {
            float p0 = __expf(sv[c][0] - mnew);
            float p1 = __expf(sv[c][1] - mnew);
            float p2 = __expf(sv[c][2] - mnew);
            float p3 = __expf(sv[c][3] - mnew);
            ts += (p0 + p1) + (p2 + p3);
            uint2 pk;
            pk.x = pack2bf(p0, p1);
            pk.y = pack2bf(p2, p3);
            *(uint2*)&Pl[wave * 1152 + lq * 72 + c * 16 + hi * 4] = pk;
        }
        ts += __shfl_xor(ts, 16);
        ts += __shfl_xor(ts, 32);
        lsum = lsum * resc + ts;
        oacc0 *= resc;
        oacc1 *= resc;

        __builtin_amdgcn_s_setprio(1);
#pragma unroll
        for (int kc = 0; kc < 2; kc++) {
            bf16x8 pf = *(const bf16x8*)&Pl[wave * 1152 + lq * 72 + kc * 32 + hi * 8];
            bf16x8 vf0 = *(const bf16x8*)((const char*)Vc + lq * 128 +
                                          (((kc * 4 + hi) ^ (lq & 7)) << 4));
            bf16x8 vf1 = *(const bf16x8*)((const char*)Vc + (16 + lq) * 128 +
                                          (((kc * 4 + hi) ^ (lq & 7)) << 4));
            oacc0 = __builtin_amdgcn_mfma_f32_16x16x32_bf16(vf0, pf, oacc0, 0, 0, 0);
            oacc1 = __builtin_amdgcn_mfma_f32_16x16x32_bf16(vf1, pf, oacc1, 0, 0, 0);
        }
        __builtin_amdgcn_s_setprio(0);

        __builtin_amdgcn_s_barrier();
        cur ^= 1;
    }

    if (n < 513) {
        float inv = 1.f / lsum;
        short* op = ob + (size_t)(b * 513 + n) * 256 + hh * 20;
        {
            uint2 pk;
            pk.x = pack2bf(oacc0[0] * inv, oacc0[1] * inv);
            pk.y = pack2bf(oacc0[2] * inv, oacc0[3] * inv);
            *(uint2*)&op[hi * 4] = pk;
        }
        if (hi == 0) {
            uint2 pk;
            pk.x = pack2bf(oacc1[0] * inv, oacc1[1] * inv);
            pk.y = pack2bf(oacc1[2] * inv, oacc1[3] * inv);
            *(uint2*)&op[16] = pk;
        }
    }
}

// ---------------- final: mean-pool patches -> LN -> head (200 -> 4) ----------------
__global__ __launch_bounds__(256) void final_kernel(const float* __restrict__ h,
                                                    const float* __restrict__ g,
                                                    const float* __restrict__ bb,
                                                    const float* __restrict__ hw,
                                                    const float* __restrict__ hb,
                                                    float* __restrict__ out) {
    __shared__ float pool[256];
    __shared__ float red[256];
    int b = blockIdx.x, t = threadIdx.x;
    float s = 0.f;
    if (t < 200) {
        const float* hp = h + b * 513 * 200 + 200 + t;
        for (int p = 0; p < 512; p++) s += hp[p * 200];
        s *= (1.f / 512.f);
    }
    pool[t] = (t < 200) ? s : 0.f;
    red[t] = pool[t];
    __syncthreads();
    for (int o = 128; o; o >>= 1) {
        if (t < o) red[t] += red[t + o];
        __syncthreads();
    }
    float mean = red[0] / 200.f;
    __syncthreads();
    float dv = (t < 200) ? (pool[t] - mean) : 0.f;
    red[t] = dv * dv;
    __syncthreads();
    for (int o = 128; o; o >>= 1) {
        if (t < o) red[t] += red[t + o];
        __syncthreads();
    }
    float var = red[0] / 200.f;
    float rstd = rsqrtf(var + 1e-6f);
    __syncthreads();
    if (t < 200) pool[t] = (pool[t] - mean) * rstd * g[t] + bb[t];
    __syncthreads();
    if (t < 4) {
        float acc = hb[t];
        for (int d2 = 0; d2 < 200; d2++) acc += pool[d2] * hw[t * 200 + d2];
        out[b * 4 + t] = acc;
    }
}

extern "C" void kernel_launch(void* const* d_in, const int* in_sizes, int n_in,
                              void* d_out, int out_size, void* d_ws, size_t ws_size,
                              hipStream_t stream) {
    const float* x        = (const float*)d_in[0];
    const float* conv1_w  = (const float*)d_in[1];
    const float* conv1_b  = (const float*)d_in[2];
    const float* gn1_g    = (const float*)d_in[3];
    const float* gn1_b    = (const float*)d_in[4];
    const float* conv2_w  = (const float*)d_in[5];
    const float* conv2_b  = (const float*)d_in[6];
    const float* gn2_g    = (const float*)d_in[7];
    const float* gn2_b    = (const float*)d_in[8];
    const float* conv3_w  = (const float*)d_in[9];
    const float* conv3_b  = (const float*)d_in[10];
    const float* gn3_g    = (const float*)d_in[11];
    const float* gn3_b    = (const float*)d_in[12];
    const float* cls_tok  = (const float*)d_in[13];
    const float* pos_emb  = (const float*)d_in[14];
    const float* time_emb = (const float*)d_in[15];
    const float* ln1_g    = (const float*)d_in[16];
    const float* ln1_b    = (const float*)d_in[17];
    const float* qkv_w    = (const float*)d_in[18];
    const float* rel_tab  = (const float*)d_in[19];
    const float* proj_w   = (const float*)d_in[20];
    const float* proj_b   = (const float*)d_in[21];
    const float* gamma1   = (const float*)d_in[22];
    const float* ln2_g    = (const float*)d_in[23];
    const float* ln2_b    = (const float*)d_in[24];
    const float* fc1_w    = (const float*)d_in[25];
    const float* fc1_b    = (const float*)d_in[26];
    const float* fc2_w    = (const float*)d_in[27];
    const float* fc2_b    = (const float*)d_in[28];
    const float* gamma2   = (const float*)d_in[29];
    const float* fcn_g    = (const float*)d_in[30];
    const float* fcn_b    = (const float*)d_in[31];
    const float* head_w   = (const float*)d_in[32];
    const float* head_b   = (const float*)d_in[33];
    const int*   rel_idx  = (const int*)d_in[34];

    // ---- workspace layout (bytes), total ~102 MB ----
    char* p = (char*)d_ws;
    float* h    = (float*)p; p += 3283200;          // 8*513*200 f32
    char* qreg = p;                                  // multi-phase region
    float* c1   = (float*)qreg;
    float* c2   = c1 + 819200;
    short* Qb   = (short*)qreg;                     // [8][10][576][32]
    short* Kb   = Qb + 1474560;
    short* Vt   = Kb + 1474560;                     // [8][10][32][576]
    short* mlp  = (short*)qreg;                     // [4104][832] (MLP phase)
    p += 9849600;
    short* y    = (short*)p; p += 2101248;          // 4104*256 bf16
    short* ob   = (short*)p; p += 2101248;          // 4104*256 bf16
    short* wqkv = (short*)p; p += 3686400;
    short* wproj= (short*)p; p += 1228800;
    short* wfc1 = (short*)p; p += 4915200;
    short* wfc2 = (short*)p; p += 3993600;
    short* biasb= (short*)p; p += 12 * 5909760;     // [12][10][513][576] bf16 = 70.9 MB
    float* stats= (float*)p;

    // ---- upfront precompute ----
    convpad_kernel<<<(7200 * 64 + 255) / 256, 256, 0, stream>>>(qkv_w, wqkv, 7200, 200, 256);
    convpad_kernel<<<(2400 * 64 + 255) / 256, 256, 0, stream>>>(proj_w, wproj, 2400, 200, 256);
    convpad_kernel<<<(9600 * 64 + 255) / 256, 256, 0, stream>>>(fc1_w, wfc1, 9600, 200, 256);
    convpad_kernel<<<(2400 * 208 + 255) / 256, 256, 0, stream>>>(fc2_w, wfc2, 2400, 800, 832);
    bias_lds_kernel<<<dim3(17, 10, 12), 256, 0, stream>>>(rel_tab, rel_idx, biasb);
    hipMemsetAsync(ob, 0, 2101248, stream);

    // ---- patch embed ----
    conv1_kernel<<<3200, 256, 0, stream>>>(x, conv1_w, conv1_b, c1);
    gn_stats_kernel<<<32, 256, 0, stream>>>(c1, stats);
    gn_apply_kernel<<<3200, 256, 0, stream>>>(c1, stats, gn1_g, gn1_b);
    conv3x1_kernel<<<3200, 256, 0, stream>>>(c1, conv2_w, conv2_b, c2);
    gn_stats_kernel<<<32, 256, 0, stream>>>(c2, stats);
    gn_apply_kernel<<<3200, 256, 0, stream>>>(c2, stats, gn2_g, gn2_b);
    conv3x1_kernel<<<3200, 256, 0, stream>>>(c2, conv3_w, conv3_b, c1);
    gn_stats_kernel<<<32, 256, 0, stream>>>(c1, stats);
    gn_apply_kernel<<<3200, 256, 0, stream>>>(c1, stats, gn3_g, gn3_b);
    embed_kernel<<<(820800 + 255) / 256, 256, 0, stream>>>(c1, cls_tok, pos_emb, time_emb, h);

    hipMemsetAsync(Qb, 0, 3 * 1474560 * 2, stream);  // zero QKV pad regions (post conv phase)

    // ---- transformer layers ----
    for (int d = 0; d < 12; d++) {
        ln_kernel<<<1026, 256, 0, stream>>>(h, ln1_g + d * 200, ln1_b + d * 200, y);
        gemm_bf<3, 32, 64><<<dim3(10, 129), 256, 0, stream>>>(y, wqkv + d * 153600,
                                                              nullptr, nullptr, nullptr, nullptr, nullptr,
                                                              4104, 600, 256, 0, 0, Qb, Kb, Vt);
        attn_mfma2<<<720, 256, 0, stream>>>(Qb, Kb, Vt, biasb + (size_t)d * 2954880, ob);
        gemm_bf<1, 32, 64><<<dim3(4, 129), 256, 0, stream>>>(ob, wproj + d * 51200, h, nullptr,
                                                             h, proj_b + d * 200, gamma1 + d * 200,
                                                             4104, 200, 256, 200, 0);
        ln_kernel<<<1026, 256, 0, stream>>>(h, ln2_g + d * 200, ln2_b + d * 200, y);
        gemm_bf<2, 32, 64><<<dim3(13, 129), 256, 0, stream>>>(y, wfc1 + d * 204800, nullptr, mlp,
                                                              nullptr, fc1_b + d * 800, nullptr,
                                                              4104, 800, 256, 832, 832);
        gemm_bf<1, 32, 64><<<dim3(4, 129), 256, 0, stream>>>(mlp, wfc2 + d * 166400, h, nullptr,
                                                             h, fc2_b + d * 200, gamma2 + d * 200,
                                                             4104, 200, 832, 200, 0);
    }

    // ---- pool + head ----
    final_kernel<<<8, 256, 0, stream>>>(h, fcn_g, fcn_b, head_w, head_b, (float*)d_out);
}

// Round 16
// 915.438 us; speedup vs baseline: 1.2013x; 1.0730x over previous
//
#include <hip/hip_runtime.h>
#include <math.h>

#define DEV static __device__ __forceinline__

typedef __attribute__((ext_vector_type(8))) short bf16x8;
typedef __attribute__((ext_vector_type(4))) float f32x4;

DEV float gelu_exact(float x) {
    return 0.5f * x * (1.0f + erff(x * 0.70710678118654752f));
}

DEV short f2bf(float f) {
    union { float f; unsigned u; } v; v.f = f;
    unsigned r = v.u + 0x7FFF + ((v.u >> 16) & 1);  // round-to-nearest-even
    return (short)(r >> 16);
}

DEV float bf2f(unsigned short b) {
    union { unsigned u; float f; } v; v.u = ((unsigned)b) << 16;
    return v.f;
}

DEV unsigned pack2bf(float a, float b) {
    return ((unsigned)(unsigned short)f2bf(a)) | (((unsigned)(unsigned short)f2bf(b)) << 16);
}

DEV void gload_lds16(const void* g, void* lds) {
    __builtin_amdgcn_global_load_lds(
        (const __attribute__((address_space(1))) void*)g,
        (__attribute__((address_space(3))) void*)lds, 16, 0, 0);
}

// ---------------- conv1: (B,1,512,200) -> (B,8,512,25), k=15 stride=8 pad=7 ----------------
__global__ void conv1_kernel(const float* __restrict__ x, const float* __restrict__ w,
                             const float* __restrict__ bias, float* __restrict__ out) {
    int idx = blockIdx.x * blockDim.x + threadIdx.x;
    const int total = 8 * 8 * 512 * 25;
    if (idx >= total) return;
    int ow = idx % 25;
    int p  = (idx / 25) % 512;
    int oc = (idx / (25 * 512)) % 8;
    int b  = idx / (25 * 512 * 8);
    const float* xp = x + b * 512 * 200 + p * 200;
    const float* wp = w + oc * 15;
    float acc = bias[oc];
    int t0 = ow * 8 - 7;
#pragma unroll
    for (int k = 0; k < 15; k++) {
        int t = t0 + k;
        if (t >= 0 && t < 200) acc += wp[k] * xp[t];
    }
    out[idx] = acc;
}

// ---------------- conv 1x3 (pad 1) on (B,8,512,25) ----------------
__global__ void conv3x1_kernel(const float* __restrict__ in, const float* __restrict__ w,
                               const float* __restrict__ bias, float* __restrict__ out) {
    int idx = blockIdx.x * blockDim.x + threadIdx.x;
    const int total = 8 * 8 * 512 * 25;
    if (idx >= total) return;
    int ow = idx % 25;
    int p  = (idx / 25) % 512;
    int oc = (idx / 12800) & 7;
    int b  = idx / 102400;
    float acc = bias[oc];
#pragma unroll
    for (int ic = 0; ic < 8; ic++) {
        const float* ip = in + b * 102400 + ic * 12800 + p * 25;
        const float* wp = w + oc * 24 + ic * 3;
        if (ow > 0)  acc += wp[0] * ip[ow - 1];
        acc += wp[1] * ip[ow];
        if (ow < 24) acc += wp[2] * ip[ow + 1];
    }
    out[idx] = acc;
}

// ---------------- groupnorm, two-stage stats ----------------
// stage 1: 512 blocks = (b,g) x 16 chunks of 1600 floats; partial sums -> part[512][2]
__global__ __launch_bounds__(256) void gn_stats1(const float* __restrict__ buf,
                                                 float* __restrict__ part) {
    int bg = blockIdx.x >> 4, ch = blockIdx.x & 15;
    const float* base = buf + (bg >> 2) * 102400 + (bg & 3) * 25600 + ch * 1600;
    float s = 0.f, s2 = 0.f;
    int t4 = threadIdx.x * 4;
#pragma unroll
    for (int off = 0; off < 1600; off += 1024) {
        int l = t4 + off;
        if (l < 1600) {
            float4 v = *(const float4*)&base[l];
            s  += v.x + v.y + v.z + v.w;
            s2 += v.x * v.x + v.y * v.y + v.z * v.z + v.w * v.w;
        }
    }
#pragma unroll
    for (int o = 32; o; o >>= 1) { s += __shfl_xor(s, o); s2 += __shfl_xor(s2, o); }
    __shared__ float red[4][2];
    if ((threadIdx.x & 63) == 0) { red[threadIdx.x >> 6][0] = s; red[threadIdx.x >> 6][1] = s2; }
    __syncthreads();
    if (threadIdx.x == 0) {
        part[blockIdx.x * 2]     = red[0][0] + red[1][0] + red[2][0] + red[3][0];
        part[blockIdx.x * 2 + 1] = red[0][1] + red[1][1] + red[2][1] + red[3][1];
    }
}

// stage 2: one tiny block reduces 16 partials per (b,g) -> stats[32][2] (mean, var)
__global__ void gn_stats2(const float* __restrict__ part, float* __restrict__ stats) {
    int i = threadIdx.x;
    if (i >= 32) return;
    float s = 0.f, q = 0.f;
    for (int c = 0; c < 16; c++) {
        s += part[(i * 16 + c) * 2];
        q += part[(i * 16 + c) * 2 + 1];
    }
    float m = s / 25600.f;
    stats[i * 2] = m;
    stats[i * 2 + 1] = q / 25600.f - m * m;
}

__global__ void gn_apply_kernel(float* __restrict__ buf, const float* __restrict__ stats,
                                const float* __restrict__ g, const float* __restrict__ bb) {
    int idx = blockIdx.x * blockDim.x + threadIdx.x;
    if (idx >= 8 * 102400) return;
    int c = (idx / 12800) & 7;
    int b = idx / 102400;
    int grp = c >> 1;
    float m = stats[(b * 4 + grp) * 2];
    float v = stats[(b * 4 + grp) * 2 + 1];
    float val = (buf[idx] - m) * rsqrtf(v + 1e-5f) * g[c] + bb[c];
    buf[idx] = gelu_exact(val);
}

// ---------------- embed ----------------
__global__ void embed_kernel(const float* __restrict__ conv, const float* __restrict__ cls,
                             const float* __restrict__ pos, const float* __restrict__ te,
                             float* __restrict__ h) {
    int idx = blockIdx.x * blockDim.x + threadIdx.x;
    if (idx >= 8 * 513 * 200) return;
    int d = idx % 200;
    int n = (idx / 200) % 513;
    int b = idx / (200 * 513);
    float val;
    if (n == 0) {
        val = cls[d] + pos[d];
    } else {
        int p = n - 1;
        int t = d >> 3;
        int c = d & 7;
        val = conv[b * 102400 + c * 12800 + p * 25 + t];
        int ch = p >> 3, tw = p & 7;
        val += pos[(1 + ch) * 200 + d] + te[tw * 200 + d];
    }
    h[idx] = val;
}

// ---------------- weight convert+pad (vec4): fp32 [R][K] -> bf16 [R][KP] ----------------
__global__ void convpad_kernel(const float* __restrict__ src, short* __restrict__ dst,
                               int R, int K, int KP) {
    int idx = blockIdx.x * blockDim.x + threadIdx.x;
    int total = R * (KP >> 2);
    if (idx >= total) return;
    int r = idx / (KP >> 2);
    int c4 = (idx - r * (KP >> 2)) << 2;
    short4 o;
    if (c4 + 3 < K) {
        float4 f = *(const float4*)&src[(size_t)r * K + c4];
        o.x = f2bf(f.x); o.y = f2bf(f.y); o.z = f2bf(f.z); o.w = f2bf(f.w);
    } else {
        o.x = (c4 + 0 < K) ? f2bf(src[(size_t)r * K + c4 + 0]) : (short)0;
        o.y = (c4 + 1 < K) ? f2bf(src[(size_t)r * K + c4 + 1]) : (short)0;
        o.z = (c4 + 2 < K) ? f2bf(src[(size_t)r * K + c4 + 2]) : (short)0;
        o.w = (c4 + 3 < K) ? f2bf(src[(size_t)r * K + c4 + 3]) : (short)0;
    }
    *(short4*)&dst[(size_t)r * KP + c4] = o;
}

// ---------------- bias precompute via LDS table: 32-row chunks (2040 blocks) ----------
__global__ __launch_bounds__(256) void bias_lds_kernel(const float* __restrict__ table,
                                                       const int* __restrict__ ridx,
                                                       short* __restrict__ bias) {
    __shared__ float tl[1908];
    const int qt = blockIdx.x, hh = blockIdx.y, d = blockIdx.z;
    const float* tab = table + d * 19080;
    for (int i = threadIdx.x; i < 1908; i += 256) tl[i] = tab[i * 10 + hh];
    __syncthreads();
    const int q0 = qt * 32;
    const int nrows = min(32, 513 - q0);
    short* obase = bias + ((size_t)d * 10 + hh) * 513 * 576;
#pragma unroll 2
    for (int lin = threadIdx.x; lin < nrows * 144; lin += 256) {
        int r = lin / 144, j = lin % 144;
        int q = q0 + r;
        const int* rp = ridx + q * 513;
        int k0 = j * 4;
        float v[4];
#pragma unroll
        for (int e = 0; e < 4; e++) {
            int k = k0 + e;
            v[e] = (k < 513) ? tl[rp[k]] : 0.f;
        }
        uint2 pk;
        pk.x = pack2bf(v[0], v[1]);
        pk.y = pack2bf(v[2], v[3]);
        *(uint2*)&obase[(size_t)q * 576 + k0] = pk;
    }
}

// ---------------- LayerNorm over D=200; 4 rows per 256-thr block (one wave/row) ----------
__global__ __launch_bounds__(256) void ln_kernel(const float* __restrict__ in,
                                                 const float* __restrict__ g,
                                                 const float* __restrict__ b,
                                                 short* __restrict__ out) {
    int row = blockIdx.x * 4 + (threadIdx.x >> 6);
    int lane = threadIdx.x & 63;
    const float* x = in + (size_t)row * 200;
    float v[4];
    float s = 0.f;
#pragma unroll
    for (int i = 0; i < 4; i++) {
        int d = lane + i * 64;
        v[i] = (d < 200) ? x[d] : 0.f;
        s += v[i];
    }
#pragma unroll
    for (int o = 32; o; o >>= 1) s += __shfl_xor(s, o);
    float mean = s * (1.f / 200.f);
    float s2 = 0.f;
#pragma unroll
    for (int i = 0; i < 4; i++) {
        int d = lane + i * 64;
        float dv = (d < 200) ? (v[i] - mean) : 0.f;
        s2 += dv * dv;
    }
#pragma unroll
    for (int o = 32; o; o >>= 1) s2 += __shfl_xor(s2, o);
    float rstd = rsqrtf(s2 * (1.f / 200.f) + 1e-6f);
#pragma unroll
    for (int i = 0; i < 4; i++) {
        int d = lane + i * 64;
        float val = (d < 200) ? (v[i] - mean) * rstd * g[d] + b[d] : 0.f;
        out[(size_t)row * 256 + d] = f2bf(val);
    }
}

// ---------------- bf16 MFMA GEMM, double-buffered K-loop (r15-proven, BM=32) ----------
// EPI 1: Cf = res + gamma[n]*(acc+bias[n])
// EPI 2: Cb = bf16(gelu(acc+bias[n])), zero pad cols N..NPout
// EPI 3: qkv scatter -> Qb[b][h][576][32] (scaled), Kb same, Vt[b][h][32][576]
template <int EPI, int BM, int BN>
__global__ __launch_bounds__(256) void gemm_bf(const short* __restrict__ A,
                                               const short* __restrict__ W,
                                               float* __restrict__ Cf,
                                               short* __restrict__ Cb,
                                               const float* __restrict__ res,
                                               const float* __restrict__ bias,
                                               const float* __restrict__ gamma,
                                               int M, int N, int KP, int ldc, int NPout,
                                               short* __restrict__ Qb = nullptr,
                                               short* __restrict__ Kb = nullptr,
                                               short* __restrict__ Vt = nullptr) {
    constexpr int WM = BM / 2, WN = BN / 2;
    constexpr int AM = WM / 16, BNr = WN / 16;
    constexpr int LOADS = (BM + BN) / 32;   // gloads per thread per k-step
    __shared__ __align__(16) short Ss[2][(BM + BN) * 64];

    const int tid = threadIdx.x;
    const int w = tid >> 6, l = tid & 63;
    const int wm = (w >> 1) * WM, wn = (w & 1) * WN;
    const int bm = blockIdx.y * BM, bn = blockIdx.x * BN;

    f32x4 acc[AM][BNr] = {};

    auto stage = [&](int buf, int k0) {
#pragma unroll
        for (int it = 0; it < LOADS; it++) {
            int lin = it * 256 + tid;
            int row = lin >> 3, slot = lin & 7;
            int srcslot = slot ^ (row & 7);
            const short* g;
            if (it * 32 < BM) {
                g = A + (size_t)(bm + row) * KP + k0 + srcslot * 8;
            } else {
                g = W + (size_t)(bn + row - BM) * KP + k0 + srcslot * 8;
            }
            gload_lds16(g, (char*)Ss[buf] + lin * 16);
        }
    };

    const int nk = KP >> 6;
    stage(0, 0);
    int cur = 0;
    for (int kstep = 0; kstep < nk; kstep++) {
        if (kstep + 1 < nk) {
            stage(cur ^ 1, (kstep + 1) << 6);
            if constexpr (LOADS == 6)      asm volatile("s_waitcnt vmcnt(6)" ::: "memory");
            else if constexpr (LOADS == 4) asm volatile("s_waitcnt vmcnt(4)" ::: "memory");
            else                           asm volatile("s_waitcnt vmcnt(3)" ::: "memory");
        } else {
            asm volatile("s_waitcnt vmcnt(0)" ::: "memory");
        }
        __builtin_amdgcn_s_barrier();

        const char* Sc = (const char*)Ss[cur];
#pragma unroll
        for (int kk = 0; kk < 2; kk++) {
            const int kbyte = kk * 64 + (l >> 4) * 16;
            bf16x8 af[AM], bfr[BNr];
#pragma unroll
            for (int i = 0; i < AM; i++) {
                int r = wm + i * 16 + (l & 15);
                af[i] = *(const bf16x8*)(Sc + r * 128 + (kbyte ^ ((r & 7) << 4)));
            }
#pragma unroll
            for (int j = 0; j < BNr; j++) {
                int r = BM + wn + j * 16 + (l & 15);
                bfr[j] = *(const bf16x8*)(Sc + r * 128 + (kbyte ^ ((r & 7) << 4)));
            }
#pragma unroll
            for (int i = 0; i < AM; i++)
#pragma unroll
                for (int j = 0; j < BNr; j++)
                    acc[i][j] = __builtin_amdgcn_mfma_f32_16x16x32_bf16(af[i], bfr[j], acc[i][j], 0, 0, 0);
        }
        __builtin_amdgcn_s_barrier();  // all waves done reading Ss[cur] before overwrite
        cur ^= 1;
    }

    const int col0 = bn + wn + (l & 15);
    const int rbase = (l >> 4) * 4;
#pragma unroll
    for (int i = 0; i < AM; i++) {
#pragma unroll
        for (int r = 0; r < 4; r++) {
            int gm = bm + wm + i * 16 + rbase + r;
            if (gm >= M) continue;
#pragma unroll
            for (int j = 0; j < BNr; j++) {
                int gn = col0 + j * 16;
                float v = acc[i][j][r];
                if (EPI == 1) {
                    if (gn < N) Cf[(size_t)gm * ldc + gn] =
                        res[(size_t)gm * ldc + gn] + gamma[gn] * (v + bias[gn]);
                } else if (EPI == 2) {
                    if (gn < NPout)
                        Cb[(size_t)gm * ldc + gn] = (gn < N) ? f2bf(gelu_exact(v + bias[gn])) : (short)0;
                } else {  // EPI 3: qkv scatter
                    if (gn < 600) {
                        int bb2 = gm / 513, n = gm - bb2 * 513;
                        if (gn < 200) {
                            int hq = gn / 20, dq = gn - hq * 20;
                            Qb[((size_t)(bb2 * 10 + hq) * 576 + n) * 32 + dq] =
                                f2bf(v * 0.22360679774997896f);
                        } else if (gn < 400) {
                            int gk = gn - 200, hk = gk / 20, dk = gk - hk * 20;
                            Kb[((size_t)(bb2 * 10 + hk) * 576 + n) * 32 + dk] = f2bf(v);
                        } else {
                            int gv = gn - 400, hv = gv / 20, dv2 = gv - hv * 20;
                            Vt[((size_t)(bb2 * 10 + hv) * 32 + dv2) * 576 + n] = f2bf(v);
                        }
                    }
                }
            }
        }
    }
}

// ---------------- MFMA flash attention v3: 4-buffer rotation, 1 barrier/tile, -----------
// bias pipelined one tile ahead. Issue order per iter kt: bias(kt+1) regs (4 loads),
// pf(kt+2) (2 gload_lds); counted vmcnt drains tile kt + bias(kt) while keeping
// pf(kt+1), bias(kt+1), pf(kt+2) in flight: vmcnt(8) for kt<7, vmcnt(6) at kt=7, 0 at kt=8.
// Single rendezvous barrier bounds wave skew to 1 iter; pf target (kt+2)&3 never
// collides with buf[kt&3] readers at skew<=1.
__global__ __launch_bounds__(256) void attn_mfma3(const short* __restrict__ Qb,
                                                  const short* __restrict__ Kb,
                                                  const short* __restrict__ Vt,
                                                  const short* __restrict__ biasb,
                                                  short* __restrict__ ob) {
    __shared__ __align__(16) short Klds[4][64 * 32];
    __shared__ __align__(16) short Vlds[4][32 * 64];
    __shared__ __align__(16) short Pl[4 * 16 * 72];

    const int orig = blockIdx.x;
    const int wg = (orig & 7) * 90 + (orig >> 3);   // XCD-chunked bijection (720 = 8*90)
    const int hh = wg / 72;
    const int rem = wg % 72;
    const int qt = rem >> 3, b = rem & 7;

    const int t = threadIdx.x, wave = t >> 6, l = t & 63;
    const int lq = l & 15, hi = l >> 4;
    const int n = qt * 64 + wave * 16 + lq;
    const int nc = min(n, 512);

    const size_t bh = (size_t)(b * 10 + hh);
    const short* Kbase = Kb + bh * 576 * 32;
    const short* Vbase = Vt + bh * 32 * 576;
    const short* Brow  = biasb + ((size_t)hh * 513 + nc) * 576;

    bf16x8 qf = *(const bf16x8*)&Qb[(bh * 576 + nc) * 32 + hi * 8];

    const int krow = t >> 2, kch = t & 3;
    const short* ksrc = Kbase + (size_t)krow * 32 + (kch ^ ((krow >> 2) & 3)) * 8;
    const int vrow = t >> 3, vch = t & 7;
    const short* vsrc = Vbase + (size_t)vrow * 576 + (vch ^ (vrow & 7)) * 8;

    float mrun = -1e30f, lsum = 0.f;
    f32x4 oacc0 = {}, oacc1 = {};
    const f32x4 zero4 = {};

    // prologue: bias tile 0 -> regs; stage tiles 0,1 into buffers 0,1
    uint2 bl_cur[4], bl_next[4];
#pragma unroll
    for (int c = 0; c < 4; c++)
        bl_cur[c] = *(const uint2*)&Brow[c * 16 + hi * 4];
    gload_lds16(ksrc, (char*)Klds[0] + t * 16);
    gload_lds16(vsrc, (char*)Vlds[0] + t * 16);
    gload_lds16(ksrc + 64 * 32, (char*)Klds[1] + t * 16);
    gload_lds16(vsrc + 64, (char*)Vlds[1] + t * 16);

    for (int kt = 0; kt < 9; kt++) {
        const int koff = kt * 64;

        if (kt < 8) {
#pragma unroll
            for (int c = 0; c < 4; c++)
                bl_next[c] = *(const uint2*)&Brow[koff + 64 + c * 16 + hi * 4];
        }
        if (kt < 7) {
            const int knext = koff + 128;
            gload_lds16(ksrc + (size_t)knext * 32, (char*)Klds[(kt + 2) & 3] + t * 16);
            gload_lds16(vsrc + knext, (char*)Vlds[(kt + 2) & 3] + t * 16);
            asm volatile("s_waitcnt vmcnt(8)" ::: "memory");
        } else if (kt == 7) {
            asm volatile("s_waitcnt vmcnt(6)" ::: "memory");
        } else {
            asm volatile("s_waitcnt vmcnt(0)" ::: "memory");
        }
        __builtin_amdgcn_s_barrier();

        const short* Kc = Klds[kt & 3];
        const short* Vc = Vlds[kt & 3];

        f32x4 s[4];
        __builtin_amdgcn_s_setprio(1);
#pragma unroll
        for (int c = 0; c < 4; c++) {
            int r = c * 16 + lq;
            bf16x8 kf = *(const bf16x8*)((const char*)Kc + r * 64 + ((hi ^ ((lq >> 2) & 3)) << 4));
            s[c] = __builtin_amdgcn_mfma_f32_16x16x32_bf16(kf, qf, zero4, 0, 0, 0);
        }
        __builtin_amdgcn_s_setprio(0);

        float sv[4][4];
        float tm = -1e30f;
#pragma unroll
        for (int c = 0; c < 4; c++) {
            float bv[4] = { bf2f((unsigned short)(bl_cur[c].x & 0xFFFF)), bf2f((unsigned short)(bl_cur[c].x >> 16)),
                            bf2f((unsigned short)(bl_cur[c].y & 0xFFFF)), bf2f((unsigned short)(bl_cur[c].y >> 16)) };
            int kglob = koff + c * 16 + hi * 4;
#pragma unroll
            for (int r = 0; r < 4; r++) {
                float val = s[c][r] + bv[r];
                if (kglob + r > 512) val = -1e30f;
                sv[c][r] = val;
                tm = fmaxf(tm, val);
            }
        }
        tm = fmaxf(tm, __shfl_xor(tm, 16));
        tm = fmaxf(tm, __shfl_xor(tm, 32));
        float mnew = fmaxf(mrun, tm);
        float resc = __expf(mrun - mnew);
        mrun = mnew;

        float ts = 0.f;
#pragma unroll
        for (int c = 0; c < 4; c++) {
            float p0 = __expf(sv[c][0] - mnew);
            float p1 = __expf(sv[c][1] - mnew);
            float p2 = __expf(sv[c][2] - mnew);
            float p3 = __expf(sv[c][3] - mnew);
            ts += (p0 + p1) + (p2 + p3);
            uint2 pk;
            pk.x = pack2bf(p0, p1);
            pk.y = pack2bf(p2, p3);
            *(uint2*)&Pl[wave * 1152 + lq * 72 + c * 16 + hi * 4] = pk;
        }
        ts += __shfl_xor(ts, 16);
        ts += __shfl_xor(ts, 32);
        lsum = lsum * resc + ts;
        oacc0 *= resc;
        oacc1 *= resc;

        __builtin_amdgcn_s_setprio(1);
#pragma unroll
        for (int kc = 0; kc < 2; kc++) {
            bf16x8 pf = *(const bf16x8*)&Pl[wave * 1152 + lq * 72 + kc * 32 + hi * 8];
            bf16x8 vf0 = *(const bf16x8*)((const char*)Vc + lq * 128 +
                                          (((kc * 4 + hi) ^ (lq & 7)) << 4));
            bf16x8 vf1 = *(const bf16x8*)((const char*)Vc + (16 + lq) * 128 +
                                          (((kc * 4 + hi) ^ (lq & 7)) << 4));
            oacc0 = __builtin_amdgcn_mfma_f32_16x16x32_bf16(vf0, pf, oacc0, 0, 0, 0);
            oacc1 = __builtin_amdgcn_mfma_f32_16x16x32_bf16(vf1, pf, oacc1, 0, 0, 0);
        }
        __builtin_amdgcn_s_setprio(0);

#pragma unroll
        for (int c = 0; c < 4; c++) bl_cur[c] = bl_next[c];
    }

    if (n < 513) {
        float inv = 1.f / lsum;
        short* op = ob + (size_t)(b * 513 + n) * 256 + hh * 20;
        {
            uint2 pk;
            pk.x = pack2bf(oacc0[0] * inv, oacc0[1] * inv);
            pk.y = pack2bf(oacc0[2] * inv, oacc0[3] * inv);
            *(uint2*)&op[hi * 4] = pk;
        }
        if (hi == 0) {
            uint2 pk;
            pk.x = pack2bf(oacc1[0] * inv, oacc1[1] * inv);
            pk.y = pack2bf(oacc1[2] * inv, oacc1[3] * inv);
            *(uint2*)&op[16] = pk;
        }
    }
}

// ---------------- final: mean-pool patches -> LN -> head (200 -> 4) ----------------
__global__ __launch_bounds__(256) void final_kernel(const float* __restrict__ h,
                                                    const float* __restrict__ g,
                                                    const float* __restrict__ bb,
                                                    const float* __restrict__ hw,
                                                    const float* __restrict__ hb,
                                                    float* __restrict__ out) {
    __shared__ float pool[256];
    __shared__ float red[256];
    int b = blockIdx.x, t = threadIdx.x;
    float s = 0.f;
    if (t < 200) {
        const float* hp = h + b * 513 * 200 + 200 + t;
        for (int p = 0; p < 512; p++) s += hp[p * 200];
        s *= (1.f / 512.f);
    }
    pool[t] = (t < 200) ? s : 0.f;
    red[t] = pool[t];
    __syncthreads();
    for (int o = 128; o; o >>= 1) {
        if (t < o) red[t] += red[t + o];
        __syncthreads();
    }
    float mean = red[0] / 200.f;
    __syncthreads();
    float dv = (t < 200) ? (pool[t] - mean) : 0.f;
    red[t] = dv * dv;
    __syncthreads();
    for (int o = 128; o; o >>= 1) {
        if (t < o) red[t] += red[t + o];
        __syncthreads();
    }
    float var = red[0] / 200.f;
    float rstd = rsqrtf(var + 1e-6f);
    __syncthreads();
    if (t < 200) pool[t] = (pool[t] - mean) * rstd * g[t] + bb[t];
    __syncthreads();
    if (t < 4) {
        float acc = hb[t];
        for (int d2 = 0; d2 < 200; d2++) acc += pool[d2] * hw[t * 200 + d2];
        out[b * 4 + t] = acc;
    }
}

extern "C" void kernel_launch(void* const* d_in, const int* in_sizes, int n_in,
                              void* d_out, int out_size, void* d_ws, size_t ws_size,
                              hipStream_t stream) {
    const float* x        = (const float*)d_in[0];
    const float* conv1_w  = (const float*)d_in[1];
    const float* conv1_b  = (const float*)d_in[2];
    const float* gn1_g    = (const float*)d_in[3];
    const float* gn1_b    = (const float*)d_in[4];
    const float* conv2_w  = (const float*)d_in[5];
    const float* conv2_b  = (const float*)d_in[6];
    const float* gn2_g    = (const float*)d_in[7];
    const float* gn2_b    = (const float*)d_in[8];
    const float* conv3_w  = (const float*)d_in[9];
    const float* conv3_b  = (const float*)d_in[10];
    const float* gn3_g    = (const float*)d_in[11];
    const float* gn3_b    = (const float*)d_in[12];
    const float* cls_tok  = (const float*)d_in[13];
    const float* pos_emb  = (const float*)d_in[14];
    const float* time_emb = (const float*)d_in[15];
    const float* ln1_g    = (const float*)d_in[16];
    const float* ln1_b    = (const float*)d_in[17];
    const float* qkv_w    = (const float*)d_in[18];
    const float* rel_tab  = (const float*)d_in[19];
    const float* proj_w   = (const float*)d_in[20];
    const float* proj_b   = (const float*)d_in[21];
    const float* gamma1   = (const float*)d_in[22];
    const float* ln2_g    = (const float*)d_in[23];
    const float* ln2_b    = (const float*)d_in[24];
    const float* fc1_w    = (const float*)d_in[25];
    const float* fc1_b    = (const float*)d_in[26];
    const float* fc2_w    = (const float*)d_in[27];
    const float* fc2_b    = (const float*)d_in[28];
    const float* gamma2   = (const float*)d_in[29];
    const float* fcn_g    = (const float*)d_in[30];
    const float* fcn_b    = (const float*)d_in[31];
    const float* head_w   = (const float*)d_in[32];
    const float* head_b   = (const float*)d_in[33];
    const int*   rel_idx  = (const int*)d_in[34];

    // ---- workspace layout (bytes), total ~102 MB ----
    char* p = (char*)d_ws;
    float* h    = (float*)p; p += 3283200;          // 8*513*200 f32
    char* qreg = p;                                  // multi-phase region
    float* c1   = (float*)qreg;
    float* c2   = c1 + 819200;
    short* Qb   = (short*)qreg;                     // [8][10][576][32]
    short* Kb   = Qb + 1474560;
    short* Vt   = Kb + 1474560;                     // [8][10][32][576]
    short* mlp  = (short*)qreg;                     // [4104][832] (MLP phase)
    p += 9849600;
    short* y    = (short*)p; p += 2101248;          // 4104*256 bf16
    short* ob   = (short*)p; p += 2101248;          // 4104*256 bf16
    short* wqkv = (short*)p; p += 3686400;
    short* wproj= (short*)p; p += 1228800;
    short* wfc1 = (short*)p; p += 4915200;
    short* wfc2 = (short*)p; p += 3993600;
    short* biasb= (short*)p; p += 12 * 5909760;     // [12][10][513][576] bf16 = 70.9 MB
    float* stats= (float*)p; p += 256;
    float* part = (float*)p;                        // 512*2 f32 partials

    // ---- upfront precompute ----
    convpad_kernel<<<(7200 * 64 + 255) / 256, 256, 0, stream>>>(qkv_w, wqkv, 7200, 200, 256);
    convpad_kernel<<<(2400 * 64 + 255) / 256, 256, 0, stream>>>(proj_w, wproj, 2400, 200, 256);
    convpad_kernel<<<(9600 * 64 + 255) / 256, 256, 0, stream>>>(fc1_w, wfc1, 9600, 200, 256);
    convpad_kernel<<<(2400 * 208 + 255) / 256, 256, 0, stream>>>(fc2_w, wfc2, 2400, 800, 832);
    bias_lds_kernel<<<dim3(17, 10, 12), 256, 0, stream>>>(rel_tab, rel_idx, biasb);
    hipMemsetAsync(ob, 0, 2101248, stream);

    // ---- patch embed ----
    conv1_kernel<<<3200, 256, 0, stream>>>(x, conv1_w, conv1_b, c1);
    gn_stats1<<<512, 256, 0, stream>>>(c1, part);
    gn_stats2<<<1, 64, 0, stream>>>(part, stats);
    gn_apply_kernel<<<3200, 256, 0, stream>>>(c1, stats, gn1_g, gn1_b);
    conv3x1_kernel<<<3200, 256, 0, stream>>>(c1, conv2_w, conv2_b, c2);
    gn_stats1<<<512, 256, 0, stream>>>(c2, part);
    gn_stats2<<<1, 64, 0, stream>>>(part, stats);
    gn_apply_kernel<<<3200, 256, 0, stream>>>(c2, stats, gn2_g, gn2_b);
    conv3x1_kernel<<<3200, 256, 0, stream>>>(c2, conv3_w, conv3_b, c1);
    gn_stats1<<<512, 256, 0, stream>>>(c1, part);
    gn_stats2<<<1, 64, 0, stream>>>(part, stats);
    gn_apply_kernel<<<3200, 256, 0, stream>>>(c1, stats, gn3_g, gn3_b);
    embed_kernel<<<(820800 + 255) / 256, 256, 0, stream>>>(c1, cls_tok, pos_emb, time_emb, h);

    hipMemsetAsync(Qb, 0, 3 * 1474560 * 2, stream);  // zero QKV pad regions (post conv phase)

    // ---- transformer layers ----
    for (int d = 0; d < 12; d++) {
        ln_kernel<<<1026, 256, 0, stream>>>(h, ln1_g + d * 200, ln1_b + d * 200, y);
        gemm_bf<3, 32, 64><<<dim3(10, 129), 256, 0, stream>>>(y, wqkv + d * 153600,
                                                              nullptr, nullptr, nullptr, nullptr, nullptr,
                                                              4104, 600, 256, 0, 0, Qb, Kb, Vt);
        attn_mfma3<<<720, 256, 0, stream>>>(Qb, Kb, Vt, biasb + (size_t)d * 2954880, ob);
        gemm_bf<1, 32, 64><<<dim3(4, 129), 256, 0, stream>>>(ob, wproj + d * 51200, h, nullptr,
                                                             h, proj_b + d * 200, gamma1 + d * 200,
                                                             4104, 200, 256, 200, 0);
        ln_kernel<<<1026, 256, 0, stream>>>(h, ln2_g + d * 200, ln2_b + d * 200, y);
        gemm_bf<2, 32, 64><<<dim3(13, 129), 256, 0, stream>>>(y, wfc1 + d * 204800, nullptr, mlp,
                                                              nullptr, fc1_b + d * 800, nullptr,
                                                              4104, 800, 256, 832, 832);
        gemm_bf<1, 32, 64><<<dim3(4, 129), 256, 0, stream>>>(mlp, wfc2 + d * 166400, h, nullptr,
                                                             h, fc2_b + d * 200, gamma2 + d * 200,
                                                             4104, 200, 832, 200, 0);
    }

    // ---- pool + head ----
    final_kernel<<<8, 256, 0, stream>>>(h, fcn_g, fcn_b, head_w, head_b, (float*)d_out);
}

// Round 17
// 896.361 us; speedup vs baseline: 1.2268x; 1.0213x over previous
//
#include <hip/hip_runtime.h>
#include <math.h>

#define DEV static __device__ __forceinline__

typedef __attribute__((ext_vector_type(8))) short bf16x8;
typedef __attribute__((ext_vector_type(4))) float f32x4;

DEV float gelu_exact(float x) {
    return 0.5f * x * (1.0f + erff(x * 0.70710678118654752f));
}

DEV short f2bf(float f) {
    union { float f; unsigned u; } v; v.f = f;
    unsigned r = v.u + 0x7FFF + ((v.u >> 16) & 1);  // round-to-nearest-even
    return (short)(r >> 16);
}

DEV float bf2f(unsigned short b) {
    union { unsigned u; float f; } v; v.u = ((unsigned)b) << 16;
    return v.f;
}

DEV unsigned pack2bf(float a, float b) {
    return ((unsigned)(unsigned short)f2bf(a)) | (((unsigned)(unsigned short)f2bf(b)) << 16);
}

DEV void gload_lds16(const void* g, void* lds) {
    __builtin_amdgcn_global_load_lds(
        (const __attribute__((address_space(1))) void*)g,
        (__attribute__((address_space(3))) void*)lds, 16, 0, 0);
}

// ---------------- conv1: (B,1,512,200) -> (B,8,512,25), k=15 stride=8 pad=7 ----------------
__global__ void conv1_kernel(const float* __restrict__ x, const float* __restrict__ w,
                             const float* __restrict__ bias, float* __restrict__ out) {
    int idx = blockIdx.x * blockDim.x + threadIdx.x;
    const int total = 8 * 8 * 512 * 25;
    if (idx >= total) return;
    int ow = idx % 25;
    int p  = (idx / 25) % 512;
    int oc = (idx / (25 * 512)) % 8;
    int b  = idx / (25 * 512 * 8);
    const float* xp = x + b * 512 * 200 + p * 200;
    const float* wp = w + oc * 15;
    float acc = bias[oc];
    int t0 = ow * 8 - 7;
#pragma unroll
    for (int k = 0; k < 15; k++) {
        int t = t0 + k;
        if (t >= 0 && t < 200) acc += wp[k] * xp[t];
    }
    out[idx] = acc;
}

// ---------------- conv 1x3 (pad 1) on (B,8,512,25) ----------------
__global__ void conv3x1_kernel(const float* __restrict__ in, const float* __restrict__ w,
                               const float* __restrict__ bias, float* __restrict__ out) {
    int idx = blockIdx.x * blockDim.x + threadIdx.x;
    const int total = 8 * 8 * 512 * 25;
    if (idx >= total) return;
    int ow = idx % 25;
    int p  = (idx / 25) % 512;
    int oc = (idx / 12800) & 7;
    int b  = idx / 102400;
    float acc = bias[oc];
#pragma unroll
    for (int ic = 0; ic < 8; ic++) {
        const float* ip = in + b * 102400 + ic * 12800 + p * 25;
        const float* wp = w + oc * 24 + ic * 3;
        if (ow > 0)  acc += wp[0] * ip[ow - 1];
        acc += wp[1] * ip[ow];
        if (ow < 24) acc += wp[2] * ip[ow + 1];
    }
    out[idx] = acc;
}

// ---------------- groupnorm, two-stage stats ----------------
__global__ __launch_bounds__(256) void gn_stats1(const float* __restrict__ buf,
                                                 float* __restrict__ part) {
    int bg = blockIdx.x >> 4, ch = blockIdx.x & 15;
    const float* base = buf + (bg >> 2) * 102400 + (bg & 3) * 25600 + ch * 1600;
    float s = 0.f, s2 = 0.f;
    int t4 = threadIdx.x * 4;
#pragma unroll
    for (int off = 0; off < 1600; off += 1024) {
        int l = t4 + off;
        if (l < 1600) {
            float4 v = *(const float4*)&base[l];
            s  += v.x + v.y + v.z + v.w;
            s2 += v.x * v.x + v.y * v.y + v.z * v.z + v.w * v.w;
        }
    }
#pragma unroll
    for (int o = 32; o; o >>= 1) { s += __shfl_xor(s, o); s2 += __shfl_xor(s2, o); }
    __shared__ float red[4][2];
    if ((threadIdx.x & 63) == 0) { red[threadIdx.x >> 6][0] = s; red[threadIdx.x >> 6][1] = s2; }
    __syncthreads();
    if (threadIdx.x == 0) {
        part[blockIdx.x * 2]     = red[0][0] + red[1][0] + red[2][0] + red[3][0];
        part[blockIdx.x * 2 + 1] = red[0][1] + red[1][1] + red[2][1] + red[3][1];
    }
}

__global__ void gn_stats2(const float* __restrict__ part, float* __restrict__ stats) {
    int i = threadIdx.x;
    if (i >= 32) return;
    float s = 0.f, q = 0.f;
    for (int c = 0; c < 16; c++) {
        s += part[(i * 16 + c) * 2];
        q += part[(i * 16 + c) * 2 + 1];
    }
    float m = s / 25600.f;
    stats[i * 2] = m;
    stats[i * 2 + 1] = q / 25600.f - m * m;
}

__global__ void gn_apply_kernel(float* __restrict__ buf, const float* __restrict__ stats,
                                const float* __restrict__ g, const float* __restrict__ bb) {
    int idx = blockIdx.x * blockDim.x + threadIdx.x;
    if (idx >= 8 * 102400) return;
    int c = (idx / 12800) & 7;
    int b = idx / 102400;
    int grp = c >> 1;
    float m = stats[(b * 4 + grp) * 2];
    float v = stats[(b * 4 + grp) * 2 + 1];
    float val = (buf[idx] - m) * rsqrtf(v + 1e-5f) * g[c] + bb[c];
    buf[idx] = gelu_exact(val);
}

// ---------------- embed ----------------
__global__ void embed_kernel(const float* __restrict__ conv, const float* __restrict__ cls,
                             const float* __restrict__ pos, const float* __restrict__ te,
                             float* __restrict__ h) {
    int idx = blockIdx.x * blockDim.x + threadIdx.x;
    if (idx >= 8 * 513 * 200) return;
    int d = idx % 200;
    int n = (idx / 200) % 513;
    int b = idx / (200 * 513);
    float val;
    if (n == 0) {
        val = cls[d] + pos[d];
    } else {
        int p = n - 1;
        int t = d >> 3;
        int c = d & 7;
        val = conv[b * 102400 + c * 12800 + p * 25 + t];
        int ch = p >> 3, tw = p & 7;
        val += pos[(1 + ch) * 200 + d] + te[tw * 200 + d];
    }
    h[idx] = val;
}

// ---------------- fused weight convert+pad: all four weight sets, one dispatch ----------
// vec4 units: seg0 qkv 7200x[200->256], seg1 proj 2400x[200->256],
//             seg2 fc1 9600x[200->256], seg3 fc2 2400x[800->832]
__global__ void convpad_all(const float* __restrict__ s0, const float* __restrict__ s1,
                            const float* __restrict__ s2, const float* __restrict__ s3,
                            short* __restrict__ d0, short* __restrict__ d1,
                            short* __restrict__ d2, short* __restrict__ d3) {
    int idx = blockIdx.x * blockDim.x + threadIdx.x;
    const float* src; short* dst; int K, KP, li;
    if (idx < 460800)       { src = s0; dst = d0; K = 200; KP = 256; li = idx; }
    else if (idx < 614400)  { src = s1; dst = d1; K = 200; KP = 256; li = idx - 460800; }
    else if (idx < 1228800) { src = s2; dst = d2; K = 200; KP = 256; li = idx - 614400; }
    else if (idx < 1728000) { src = s3; dst = d3; K = 800; KP = 832; li = idx - 1228800; }
    else return;
    int r = li / (KP >> 2);
    int c4 = (li - r * (KP >> 2)) << 2;
    short4 o;
    if (c4 + 3 < K) {
        float4 f = *(const float4*)&src[(size_t)r * K + c4];
        o.x = f2bf(f.x); o.y = f2bf(f.y); o.z = f2bf(f.z); o.w = f2bf(f.w);
    } else {
        o.x = (c4 + 0 < K) ? f2bf(src[(size_t)r * K + c4 + 0]) : (short)0;
        o.y = (c4 + 1 < K) ? f2bf(src[(size_t)r * K + c4 + 1]) : (short)0;
        o.z = (c4 + 2 < K) ? f2bf(src[(size_t)r * K + c4 + 2]) : (short)0;
        o.w = (c4 + 3 < K) ? f2bf(src[(size_t)r * K + c4 + 3]) : (short)0;
    }
    *(short4*)&dst[(size_t)r * KP + c4] = o;
}

// ---------------- bias precompute: 2 heads per block, float2 table stage ---------------
// Block (qt 0..16, hy 0..4, d): heads h0=2*hy, h0+1 share one ridx-row read per gather.
// grid (17,5,12) = 1020 blocks; LDS 15.3 KB.
__global__ __launch_bounds__(256) void bias_lds_kernel(const float* __restrict__ table,
                                                       const int* __restrict__ ridx,
                                                       short* __restrict__ bias) {
    __shared__ float tl0[1908], tl1[1908];
    const int qt = blockIdx.x, hy = blockIdx.y, d = blockIdx.z;
    const int h0 = hy * 2;
    const float* tab = table + d * 19080;
    for (int i = threadIdx.x; i < 1908; i += 256) {
        float2 v = *(const float2*)&tab[i * 10 + h0];   // h0 even -> 8B aligned
        tl0[i] = v.x;
        tl1[i] = v.y;
    }
    __syncthreads();
    const int q0 = qt * 32;
    const int nrows = min(32, 513 - q0);
    short* ob0 = bias + ((size_t)d * 10 + h0) * 513 * 576;
    short* ob1 = ob0 + 513 * 576;
#pragma unroll 2
    for (int lin = threadIdx.x; lin < nrows * 144; lin += 256) {
        int r = lin / 144, j = lin % 144;
        int q = q0 + r;
        const int* rp = ridx + q * 513;
        int k0 = j * 4;
        float a[4], c[4];
#pragma unroll
        for (int e = 0; e < 4; e++) {
            int k = k0 + e;
            if (k < 513) {
                int t = rp[k];
                a[e] = tl0[t];
                c[e] = tl1[t];
            } else {
                a[e] = 0.f;
                c[e] = 0.f;
            }
        }
        uint2 p0, p1;
        p0.x = pack2bf(a[0], a[1]); p0.y = pack2bf(a[2], a[3]);
        p1.x = pack2bf(c[0], c[1]); p1.y = pack2bf(c[2], c[3]);
        *(uint2*)&ob0[(size_t)q * 576 + k0] = p0;
        *(uint2*)&ob1[(size_t)q * 576 + k0] = p1;
    }
}

// ---------------- LayerNorm over D=200; 4 rows per 256-thr block (one wave/row) ----------
__global__ __launch_bounds__(256) void ln_kernel(const float* __restrict__ in,
                                                 const float* __restrict__ g,
                                                 const float* __restrict__ b,
                                                 short* __restrict__ out) {
    int row = blockIdx.x * 4 + (threadIdx.x >> 6);
    int lane = threadIdx.x & 63;
    const float* x = in + (size_t)row * 200;
    float v[4];
    float s = 0.f;
#pragma unroll
    for (int i = 0; i < 4; i++) {
        int d = lane + i * 64;
        v[i] = (d < 200) ? x[d] : 0.f;
        s += v[i];
    }
#pragma unroll
    for (int o = 32; o; o >>= 1) s += __shfl_xor(s, o);
    float mean = s * (1.f / 200.f);
    float s2 = 0.f;
#pragma unroll
    for (int i = 0; i < 4; i++) {
        int d = lane + i * 64;
        float dv = (d < 200) ? (v[i] - mean) : 0.f;
        s2 += dv * dv;
    }
#pragma unroll
    for (int o = 32; o; o >>= 1) s2 += __shfl_xor(s2, o);
    float rstd = rsqrtf(s2 * (1.f / 200.f) + 1e-6f);
#pragma unroll
    for (int i = 0; i < 4; i++) {
        int d = lane + i * 64;
        float val = (d < 200) ? (v[i] - mean) * rstd * g[d] + b[d] : 0.f;
        out[(size_t)row * 256 + d] = f2bf(val);
    }
}

// ---------------- bf16 MFMA GEMM, double-buffered K-loop (BM=32 proven) ----------------
// EPI 1: Cf = res + gamma[n]*(acc+bias[n])
// EPI 2: Cb = bf16(gelu(acc+bias[n])), zero pad cols N..NPout
// EPI 3: qkv scatter -> Qb[b][h][576][32] (scaled), Kb same, Vt[b][h][32][576]
template <int EPI, int BM, int BN>
__global__ __launch_bounds__(256) void gemm_bf(const short* __restrict__ A,
                                               const short* __restrict__ W,
                                               float* __restrict__ Cf,
                                               short* __restrict__ Cb,
                                               const float* __restrict__ res,
                                               const float* __restrict__ bias,
                                               const float* __restrict__ gamma,
                                               int M, int N, int KP, int ldc, int NPout,
                                               short* __restrict__ Qb = nullptr,
                                               short* __restrict__ Kb = nullptr,
                                               short* __restrict__ Vt = nullptr) {
    constexpr int WM = BM / 2, WN = BN / 2;
    constexpr int AM = WM / 16, BNr = WN / 16;
    constexpr int LOADS = (BM + BN) / 32;   // gloads per thread per k-step
    __shared__ __align__(16) short Ss[2][(BM + BN) * 64];

    const int tid = threadIdx.x;
    const int w = tid >> 6, l = tid & 63;
    const int wm = (w >> 1) * WM, wn = (w & 1) * WN;
    const int bm = blockIdx.y * BM, bn = blockIdx.x * BN;

    f32x4 acc[AM][BNr] = {};

    auto stage = [&](int buf, int k0) {
#pragma unroll
        for (int it = 0; it < LOADS; it++) {
            int lin = it * 256 + tid;
            int row = lin >> 3, slot = lin & 7;
            int srcslot = slot ^ (row & 7);
            const short* g;
            if (it * 32 < BM) {
                g = A + (size_t)(bm + row) * KP + k0 + srcslot * 8;
            } else {
                g = W + (size_t)(bn + row - BM) * KP + k0 + srcslot * 8;
            }
            gload_lds16(g, (char*)Ss[buf] + lin * 16);
        }
    };

    const int nk = KP >> 6;
    stage(0, 0);
    int cur = 0;
    for (int kstep = 0; kstep < nk; kstep++) {
        if (kstep + 1 < nk) {
            stage(cur ^ 1, (kstep + 1) << 6);
            if constexpr (LOADS == 6)      asm volatile("s_waitcnt vmcnt(6)" ::: "memory");
            else if constexpr (LOADS == 4) asm volatile("s_waitcnt vmcnt(4)" ::: "memory");
            else                           asm volatile("s_waitcnt vmcnt(3)" ::: "memory");
        } else {
            asm volatile("s_waitcnt vmcnt(0)" ::: "memory");
        }
        __builtin_amdgcn_s_barrier();

        const char* Sc = (const char*)Ss[cur];
#pragma unroll
        for (int kk = 0; kk < 2; kk++) {
            const int kbyte = kk * 64 + (l >> 4) * 16;
            bf16x8 af[AM], bfr[BNr];
#pragma unroll
            for (int i = 0; i < AM; i++) {
                int r = wm + i * 16 + (l & 15);
                af[i] = *(const bf16x8*)(Sc + r * 128 + (kbyte ^ ((r & 7) << 4)));
            }
#pragma unroll
            for (int j = 0; j < BNr; j++) {
                int r = BM + wn + j * 16 + (l & 15);
                bfr[j] = *(const bf16x8*)(Sc + r * 128 + (kbyte ^ ((r & 7) << 4)));
            }
#pragma unroll
            for (int i = 0; i < AM; i++)
#pragma unroll
                for (int j = 0; j < BNr; j++)
                    acc[i][j] = __builtin_amdgcn_mfma_f32_16x16x32_bf16(af[i], bfr[j], acc[i][j], 0, 0, 0);
        }
        __builtin_amdgcn_s_barrier();  // all waves done reading Ss[cur] before overwrite
        cur ^= 1;
    }

    const int col0 = bn + wn + (l & 15);
    const int rbase = (l >> 4) * 4;
#pragma unroll
    for (int i = 0; i < AM; i++) {
#pragma unroll
        for (int r = 0; r < 4; r++) {
            int gm = bm + wm + i * 16 + rbase + r;
            if (gm >= M) continue;
#pragma unroll
            for (int j = 0; j < BNr; j++) {
                int gn = col0 + j * 16;
                float v = acc[i][j][r];
                if (EPI == 1) {
                    if (gn < N) Cf[(size_t)gm * ldc + gn] =
                        res[(size_t)gm * ldc + gn] + gamma[gn] * (v + bias[gn]);
                } else if (EPI == 2) {
                    if (gn < NPout)
                        Cb[(size_t)gm * ldc + gn] = (gn < N) ? f2bf(gelu_exact(v + bias[gn])) : (short)0;
                } else {  // EPI 3: qkv scatter
                    if (gn < 600) {
                        int bb2 = gm / 513, n = gm - bb2 * 513;
                        if (gn < 200) {
                            int hq = gn / 20, dq = gn - hq * 20;
                            Qb[((size_t)(bb2 * 10 + hq) * 576 + n) * 32 + dq] =
                                f2bf(v * 0.22360679774997896f);
                        } else if (gn < 400) {
                            int gk = gn - 200, hk = gk / 20, dk = gk - hk * 20;
                            Kb[((size_t)(bb2 * 10 + hk) * 576 + n) * 32 + dk] = f2bf(v);
                        } else {
                            int gv = gn - 400, hv = gv / 20, dv2 = gv - hv * 20;
                            Vt[((size_t)(bb2 * 10 + hv) * 32 + dv2) * 576 + n] = f2bf(v);
                        }
                    }
                }
            }
        }
    }
}

// ---------------- MFMA flash attention v3: 4-buffer rotation, 1 barrier/tile, -----------
// bias pipelined one tile ahead (r16-proven).
__global__ __launch_bounds__(256) void attn_mfma3(const short* __restrict__ Qb,
                                                  const short* __restrict__ Kb,
                                                  const short* __restrict__ Vt,
                                                  const short* __restrict__ biasb,
                                                  short* __restrict__ ob) {
    __shared__ __align__(16) short Klds[4][64 * 32];
    __shared__ __align__(16) short Vlds[4][32 * 64];
    __shared__ __align__(16) short Pl[4 * 16 * 72];

    const int orig = blockIdx.x;
    const int wg = (orig & 7) * 90 + (orig >> 3);   // XCD-chunked bijection (720 = 8*90)
    const int hh = wg / 72;
    const int rem = wg % 72;
    const int qt = rem >> 3, b = rem & 7;

    const int t = threadIdx.x, wave = t >> 6, l = t & 63;
    const int lq = l & 15, hi = l >> 4;
    const int n = qt * 64 + wave * 16 + lq;
    const int nc = min(n, 512);

    const size_t bh = (size_t)(b * 10 + hh);
    const short* Kbase = Kb + bh * 576 * 32;
    const short* Vbase = Vt + bh * 32 * 576;
    const short* Brow  = biasb + ((size_t)hh * 513 + nc) * 576;

    bf16x8 qf = *(const bf16x8*)&Qb[(bh * 576 + nc) * 32 + hi * 8];

    const int krow = t >> 2, kch = t & 3;
    const short* ksrc = Kbase + (size_t)krow * 32 + (kch ^ ((krow >> 2) & 3)) * 8;
    const int vrow = t >> 3, vch = t & 7;
    const short* vsrc = Vbase + (size_t)vrow * 576 + (vch ^ (vrow & 7)) * 8;

    float mrun = -1e30f, lsum = 0.f;
    f32x4 oacc0 = {}, oacc1 = {};
    const f32x4 zero4 = {};

    uint2 bl_cur[4], bl_next[4];
#pragma unroll
    for (int c = 0; c < 4; c++)
        bl_cur[c] = *(const uint2*)&Brow[c * 16 + hi * 4];
    gload_lds16(ksrc, (char*)Klds[0] + t * 16);
    gload_lds16(vsrc, (char*)Vlds[0] + t * 16);
    gload_lds16(ksrc + 64 * 32, (char*)Klds[1] + t * 16);
    gload_lds16(vsrc + 64, (char*)Vlds[1] + t * 16);

    for (int kt = 0; kt < 9; kt++) {
        const int koff = kt * 64;

        if (kt < 8) {
#pragma unroll
            for (int c = 0; c < 4; c++)
                bl_next[c] = *(const uint2*)&Brow[koff + 64 + c * 16 + hi * 4];
        }
        if (kt < 7) {
            const int knext = koff + 128;
            gload_lds16(ksrc + (size_t)knext * 32, (char*)Klds[(kt + 2) & 3] + t * 16);
            gload_lds16(vsrc + knext, (char*)Vlds[(kt + 2) & 3] + t * 16);
            asm volatile("s_waitcnt vmcnt(8)" ::: "memory");
        } else if (kt == 7) {
            asm volatile("s_waitcnt vmcnt(6)" ::: "memory");
        } else {
            asm volatile("s_waitcnt vmcnt(0)" ::: "memory");
        }
        __builtin_amdgcn_s_barrier();

        const short* Kc = Klds[kt & 3];
        const short* Vc = Vlds[kt & 3];

        f32x4 s[4];
        __builtin_amdgcn_s_setprio(1);
#pragma unroll
        for (int c = 0; c < 4; c++) {
            int r = c * 16 + lq;
            bf16x8 kf = *(const bf16x8*)((const char*)Kc + r * 64 + ((hi ^ ((lq >> 2) & 3)) << 4));
            s[c] = __builtin_amdgcn_mfma_f32_16x16x32_bf16(kf, qf, zero4, 0, 0, 0);
        }
        __builtin_amdgcn_s_setprio(0);

        float sv[4][4];
        float tm = -1e30f;
#pragma unroll
        for (int c = 0; c < 4; c++) {
            float bv[4] = { bf2f((unsigned short)(bl_cur[c].x & 0xFFFF)), bf2f((unsigned short)(bl_cur[c].x >> 16)),
                            bf2f((unsigned short)(bl_cur[c].y & 0xFFFF)), bf2f((unsigned short)(bl_cur[c].y >> 16)) };
            int kglob = koff + c * 16 + hi * 4;
#pragma unroll
            for (int r = 0; r < 4; r++) {
                float val = s[c][r] + bv[r];
                if (kglob + r > 512) val = -1e30f;
                sv[c][r] = val;
                tm = fmaxf(tm, val);
            }
        }
        tm = fmaxf(tm, __shfl_xor(tm, 16));
        tm = fmaxf(tm, __shfl_xor(tm, 32));
        float mnew = fmaxf(mrun, tm);
        float resc = __expf(mrun - mnew);
        mrun = mnew;

        float ts = 0.f;
#pragma unroll
        for (int c = 0; c < 4; c++) {
            float p0 = __expf(sv[c][0] - mnew);
            float p1 = __expf(sv[c][1] - mnew);
            float p2 = __expf(sv[c][2] - mnew);
            float p3 = __expf(sv[c][3] - mnew);
            ts += (p0 + p1) + (p2 + p3);
            uint2 pk;
            pk.x = pack2bf(p0, p1);
            pk.y = pack2bf(p2, p3);
            *(uint2*)&Pl[wave * 1152 + lq * 72 + c * 16 + hi * 4] = pk;
        }
        ts += __shfl_xor(ts, 16);
        ts += __shfl_xor(ts, 32);
        lsum = lsum * resc + ts;
        oacc0 *= resc;
        oacc1 *= resc;

        __builtin_amdgcn_s_setprio(1);
#pragma unroll
        for (int kc = 0; kc < 2; kc++) {
            bf16x8 pf = *(const bf16x8*)&Pl[wave * 1152 + lq * 72 + kc * 32 + hi * 8];
            bf16x8 vf0 = *(const bf16x8*)((const char*)Vc + lq * 128 +
                                          (((kc * 4 + hi) ^ (lq & 7)) << 4));
            bf16x8 vf1 = *(const bf16x8*)((const char*)Vc + (16 + lq) * 128 +
                                          (((kc * 4 + hi) ^ (lq & 7)) << 4));
            oacc0 = __builtin_amdgcn_mfma_f32_16x16x32_bf16(vf0, pf, oacc0, 0, 0, 0);
            oacc1 = __builtin_amdgcn_mfma_f32_16x16x32_bf16(vf1, pf, oacc1, 0, 0, 0);
        }
        __builtin_amdgcn_s_setprio(0);

#pragma unroll
        for (int c = 0; c < 4; c++) bl_cur[c] = bl_next[c];
    }

    if (n < 513) {
        float inv = 1.f / lsum;
        short* op = ob + (size_t)(b * 513 + n) * 256 + hh * 20;
        {
            uint2 pk;
            pk.x = pack2bf(oacc0[0] * inv, oacc0[1] * inv);
            pk.y = pack2bf(oacc0[2] * inv, oacc0[3] * inv);
            *(uint2*)&op[hi * 4] = pk;
        }
        if (hi == 0) {
            uint2 pk;
            pk.x = pack2bf(oacc1[0] * inv, oacc1[1] * inv);
            pk.y = pack2bf(oacc1[2] * inv, oacc1[3] * inv);
            *(uint2*)&op[16] = pk;
        }
    }
}

// ---------------- final: mean-pool patches -> LN -> head (200 -> 4) ----------------
__global__ __launch_bounds__(256) void final_kernel(const float* __restrict__ h,
                                                    const float* __restrict__ g,
                                                    const float* __restrict__ bb,
                                                    const float* __restrict__ hw,
                                                    const float* __restrict__ hb,
                                                    float* __restrict__ out) {
    __shared__ float pool[256];
    __shared__ float red[256];
    int b = blockIdx.x, t = threadIdx.x;
    float s = 0.f;
    if (t < 200) {
        const float* hp = h + b * 513 * 200 + 200 + t;
        for (int p = 0; p < 512; p++) s += hp[p * 200];
        s *= (1.f / 512.f);
    }
    pool[t] = (t < 200) ? s : 0.f;
    red[t] = pool[t];
    __syncthreads();
    for (int o = 128; o; o >>= 1) {
        if (t < o) red[t] += red[t + o];
        __syncthreads();
    }
    float mean = red[0] / 200.f;
    __syncthreads();
    float dv = (t < 200) ? (pool[t] - mean) : 0.f;
    red[t] = dv * dv;
    __syncthreads();
    for (int o = 128; o; o >>= 1) {
        if (t < o) red[t] += red[t + o];
        __syncthreads();
    }
    float var = red[0] / 200.f;
    float rstd = rsqrtf(var + 1e-6f);
    __syncthreads();
    if (t < 200) pool[t] = (pool[t] - mean) * rstd * g[t] + bb[t];
    __syncthreads();
    if (t < 4) {
        float acc = hb[t];
        for (int d2 = 0; d2 < 200; d2++) acc += pool[d2] * hw[t * 200 + d2];
        out[b * 4 + t] = acc;
    }
}

extern "C" void kernel_launch(void* const* d_in, const int* in_sizes, int n_in,
                              void* d_out, int out_size, void* d_ws, size_t ws_size,
                              hipStream_t stream) {
    const float* x        = (const float*)d_in[0];
    const float* conv1_w  = (const float*)d_in[1];
    const float* conv1_b  = (const float*)d_in[2];
    const float* gn1_g    = (const float*)d_in[3];
    const float* gn1_b    = (const float*)d_in[4];
    const float* conv2_w  = (const float*)d_in[5];
    const float* conv2_b  = (const float*)d_in[6];
    const float* gn2_g    = (const float*)d_in[7];
    const float* gn2_b    = (const float*)d_in[8];
    const float* conv3_w  = (const float*)d_in[9];
    const float* conv3_b  = (const float*)d_in[10];
    const float* gn3_g    = (const float*)d_in[11];
    const float* gn3_b    = (const float*)d_in[12];
    const float* cls_tok  = (const float*)d_in[13];
    const float* pos_emb  = (const float*)d_in[14];
    const float* time_emb = (const float*)d_in[15];
    const float* ln1_g    = (const float*)d_in[16];
    const float* ln1_b    = (const float*)d_in[17];
    const float* qkv_w    = (const float*)d_in[18];
    const float* rel_tab  = (const float*)d_in[19];
    const float* proj_w   = (const float*)d_in[20];
    const float* proj_b   = (const float*)d_in[21];
    const float* gamma1   = (const float*)d_in[22];
    const float* ln2_g    = (const float*)d_in[23];
    const float* ln2_b    = (const float*)d_in[24];
    const float* fc1_w    = (const float*)d_in[25];
    const float* fc1_b    = (const float*)d_in[26];
    const float* fc2_w    = (const float*)d_in[27];
    const float* fc2_b    = (const float*)d_in[28];
    const float* gamma2   = (const float*)d_in[29];
    const float* fcn_g    = (const float*)d_in[30];
    const float* fcn_b    = (const float*)d_in[31];
    const float* head_w   = (const float*)d_in[32];
    const float* head_b   = (const float*)d_in[33];
    const int*   rel_idx  = (const int*)d_in[34];

    // ---- workspace layout (bytes), total ~102 MB ----
    char* p = (char*)d_ws;
    float* h    = (float*)p; p += 3283200;          // 8*513*200 f32
    char* qreg = p;                                  // multi-phase region
    float* c1   = (float*)qreg;
    float* c2   = c1 + 819200;
    short* Qb   = (short*)qreg;                     // [8][10][576][32]
    short* Kb   = Qb + 1474560;
    short* Vt   = Kb + 1474560;                     // [8][10][32][576]
    short* mlp  = (short*)qreg;                     // [4104][832] (MLP phase)
    p += 9849600;
    short* y    = (short*)p; p += 2101248;          // 4104*256 bf16
    short* ob   = (short*)p; p += 2101248;          // 4104*256 bf16
    short* wqkv = (short*)p; p += 3686400;
    short* wproj= (short*)p; p += 1228800;
    short* wfc1 = (short*)p; p += 4915200;
    short* wfc2 = (short*)p; p += 3993600;
    short* biasb= (short*)p; p += 12 * 5909760;     // [12][10][513][576] bf16 = 70.9 MB
    float* stats= (float*)p; p += 256;
    float* part = (float*)p;                        // 512*2 f32 partials

    // ---- upfront precompute ----
    convpad_all<<<6750, 256, 0, stream>>>(qkv_w, proj_w, fc1_w, fc2_w, wqkv, wproj, wfc1, wfc2);
    bias_lds_kernel<<<dim3(17, 5, 12), 256, 0, stream>>>(rel_tab, rel_idx, biasb);
    hipMemsetAsync(ob, 0, 2101248, stream);

    // ---- patch embed ----
    conv1_kernel<<<3200, 256, 0, stream>>>(x, conv1_w, conv1_b, c1);
    gn_stats1<<<512, 256, 0, stream>>>(c1, part);
    gn_stats2<<<1, 64, 0, stream>>>(part, stats);
    gn_apply_kernel<<<3200, 256, 0, stream>>>(c1, stats, gn1_g, gn1_b);
    conv3x1_kernel<<<3200, 256, 0, stream>>>(c1, conv2_w, conv2_b, c2);
    gn_stats1<<<512, 256, 0, stream>>>(c2, part);
    gn_stats2<<<1, 64, 0, stream>>>(part, stats);
    gn_apply_kernel<<<3200, 256, 0, stream>>>(c2, stats, gn2_g, gn2_b);
    conv3x1_kernel<<<3200, 256, 0, stream>>>(c2, conv3_w, conv3_b, c1);
    gn_stats1<<<512, 256, 0, stream>>>(c1, part);
    gn_stats2<<<1, 64, 0, stream>>>(part, stats);
    gn_apply_kernel<<<3200, 256, 0, stream>>>(c1, stats, gn3_g, gn3_b);
    embed_kernel<<<(820800 + 255) / 256, 256, 0, stream>>>(c1, cls_tok, pos_emb, time_emb, h);

    hipMemsetAsync(Qb, 0, 3 * 1474560 * 2, stream);  // zero QKV pad regions (post conv phase)

    // ---- transformer layers ----
    for (int d = 0; d < 12; d++) {
        ln_kernel<<<1026, 256, 0, stream>>>(h, ln1_g + d * 200, ln1_b + d * 200, y);
        gemm_bf<3, 32, 64><<<dim3(10, 129), 256, 0, stream>>>(y, wqkv + d * 153600,
                                                              nullptr, nullptr, nullptr, nullptr, nullptr,
                                                              4104, 600, 256, 0, 0, Qb, Kb, Vt);
        attn_mfma3<<<720, 256, 0, stream>>>(Qb, Kb, Vt, biasb + (size_t)d * 2954880, ob);
        gemm_bf<1, 32, 64><<<dim3(4, 129), 256, 0, stream>>>(ob, wproj + d * 51200, h, nullptr,
                                                             h, proj_b + d * 200, gamma1 + d * 200,
                                                             4104, 200, 256, 200, 0);
        ln_kernel<<<1026, 256, 0, stream>>>(h, ln2_g + d * 200, ln2_b + d * 200, y);
        gemm_bf<2, 32, 64><<<dim3(13, 129), 256, 0, stream>>>(y, wfc1 + d * 204800, nullptr, mlp,
                                                              nullptr, fc1_b + d * 800, nullptr,
                                                              4104, 800, 256, 832, 832);
        gemm_bf<1, 32, 64><<<dim3(4, 129), 256, 0, stream>>>(mlp, wfc2 + d * 166400, h, nullptr,
                                                             h, fc2_b + d * 200, gamma2 + d * 200,
                                                             4104, 200, 832, 200, 0);
    }

    // ---- pool + head ----
    final_kernel<<<8, 256, 0, stream>>>(h, fcn_g, fcn_b, head_w, head_b, (float*)d_out);
}

// Round 18
// 885.334 us; speedup vs baseline: 1.2421x; 1.0125x over previous
//
#include <hip/hip_runtime.h>
#include <math.h>

#define DEV static __device__ __forceinline__

typedef __attribute__((ext_vector_type(8))) short bf16x8;
typedef __attribute__((ext_vector_type(4))) float f32x4;

DEV float gelu_exact(float x) {
    return 0.5f * x * (1.0f + erff(x * 0.70710678118654752f));
}

DEV short f2bf(float f) {
    union { float f; unsigned u; } v; v.f = f;
    unsigned r = v.u + 0x7FFF + ((v.u >> 16) & 1);  // round-to-nearest-even
    return (short)(r >> 16);
}

DEV float bf2f(unsigned short b) {
    union { unsigned u; float f; } v; v.u = ((unsigned)b) << 16;
    return v.f;
}

DEV unsigned pack2bf(float a, float b) {
    return ((unsigned)(unsigned short)f2bf(a)) | (((unsigned)(unsigned short)f2bf(b)) << 16);
}

DEV void gload_lds16(const void* g, void* lds) {
    __builtin_amdgcn_global_load_lds(
        (const __attribute__((address_space(1))) void*)g,
        (__attribute__((address_space(3))) void*)lds, 16, 0, 0);
}

// ---------------- conv1: (B,1,512,200) -> (B,8,512,25), k=15 stride=8 pad=7 ----------------
__global__ void conv1_kernel(const float* __restrict__ x, const float* __restrict__ w,
                             const float* __restrict__ bias, float* __restrict__ out) {
    int idx = blockIdx.x * blockDim.x + threadIdx.x;
    const int total = 8 * 8 * 512 * 25;
    if (idx >= total) return;
    int ow = idx % 25;
    int p  = (idx / 25) % 512;
    int oc = (idx / (25 * 512)) % 8;
    int b  = idx / (25 * 512 * 8);
    const float* xp = x + b * 512 * 200 + p * 200;
    const float* wp = w + oc * 15;
    float acc = bias[oc];
    int t0 = ow * 8 - 7;
#pragma unroll
    for (int k = 0; k < 15; k++) {
        int t = t0 + k;
        if (t >= 0 && t < 200) acc += wp[k] * xp[t];
    }
    out[idx] = acc;
}

// ---------------- conv 1x3 (pad 1) on (B,8,512,25) ----------------
__global__ void conv3x1_kernel(const float* __restrict__ in, const float* __restrict__ w,
                               const float* __restrict__ bias, float* __restrict__ out) {
    int idx = blockIdx.x * blockDim.x + threadIdx.x;
    const int total = 8 * 8 * 512 * 25;
    if (idx >= total) return;
    int ow = idx % 25;
    int p  = (idx / 25) % 512;
    int oc = (idx / 12800) & 7;
    int b  = idx / 102400;
    float acc = bias[oc];
#pragma unroll
    for (int ic = 0; ic < 8; ic++) {
        const float* ip = in + b * 102400 + ic * 12800 + p * 25;
        const float* wp = w + oc * 24 + ic * 3;
        if (ow > 0)  acc += wp[0] * ip[ow - 1];
        acc += wp[1] * ip[ow];
        if (ow < 24) acc += wp[2] * ip[ow + 1];
    }
    out[idx] = acc;
}

// ---------------- groupnorm stage-1 partials: 512 blocks = (b,g) x 16 chunks ------------
__global__ __launch_bounds__(256) void gn_stats1(const float* __restrict__ buf,
                                                 float* __restrict__ part) {
    int bg = blockIdx.x >> 4, ch = blockIdx.x & 15;
    const float* base = buf + (bg >> 2) * 102400 + (bg & 3) * 25600 + ch * 1600;
    float s = 0.f, s2 = 0.f;
    int t4 = threadIdx.x * 4;
#pragma unroll
    for (int off = 0; off < 1600; off += 1024) {
        int l = t4 + off;
        if (l < 1600) {
            float4 v = *(const float4*)&base[l];
            s  += v.x + v.y + v.z + v.w;
            s2 += v.x * v.x + v.y * v.y + v.z * v.z + v.w * v.w;
        }
    }
#pragma unroll
    for (int o = 32; o; o >>= 1) { s += __shfl_xor(s, o); s2 += __shfl_xor(s2, o); }
    __shared__ float red[4][2];
    if ((threadIdx.x & 63) == 0) { red[threadIdx.x >> 6][0] = s; red[threadIdx.x >> 6][1] = s2; }
    __syncthreads();
    if (threadIdx.x == 0) {
        part[blockIdx.x * 2]     = red[0][0] + red[1][0] + red[2][0] + red[3][0];
        part[blockIdx.x * 2 + 1] = red[0][1] + red[1][1] + red[2][1] + red[3][1];
    }
}

// ---------------- gn apply + gelu; inline stage-2 (one (b,grp) per block) ---------------
__global__ __launch_bounds__(256) void gn_apply_kernel(float* __restrict__ buf,
                                                       const float* __restrict__ part,
                                                       const float* __restrict__ g,
                                                       const float* __restrict__ bb) {
    __shared__ float sm, sr;
    int idx0 = blockIdx.x * 256;
    if (threadIdx.x == 0) {
        int c = (idx0 / 12800) & 7;
        int b = idx0 / 102400;
        int bg = b * 4 + (c >> 1);
        float s = 0.f, q = 0.f;
#pragma unroll
        for (int e = 0; e < 16; e++) {
            s += part[(bg * 16 + e) * 2];
            q += part[(bg * 16 + e) * 2 + 1];
        }
        float m = s / 25600.f;
        sm = m;
        sr = rsqrtf(q / 25600.f - m * m + 1e-5f);
    }
    __syncthreads();
    int idx = idx0 + threadIdx.x;
    int c = (idx / 12800) & 7;
    float val = (buf[idx] - sm) * sr * g[c] + bb[c];
    buf[idx] = gelu_exact(val);
}

// ---------------- embed, fused with gn3 apply + gelu (stats from part, LDS-staged) ------
__global__ __launch_bounds__(256) void embed_kernel(const float* __restrict__ conv,
                                                    const float* __restrict__ part,
                                                    const float* __restrict__ g3,
                                                    const float* __restrict__ b3,
                                                    const float* __restrict__ cls,
                                                    const float* __restrict__ pos,
                                                    const float* __restrict__ te,
                                                    float* __restrict__ h) {
    __shared__ float sm[32], sr[32];
    if (threadIdx.x < 32) {
        int bg = threadIdx.x;
        float s = 0.f, q = 0.f;
#pragma unroll
        for (int e = 0; e < 16; e++) {
            s += part[(bg * 16 + e) * 2];
            q += part[(bg * 16 + e) * 2 + 1];
        }
        float m = s / 25600.f;
        sm[bg] = m;
        sr[bg] = rsqrtf(q / 25600.f - m * m + 1e-5f);
    }
    __syncthreads();
    int idx = blockIdx.x * blockDim.x + threadIdx.x;
    if (idx >= 8 * 513 * 200) return;
    int d = idx % 200;
    int n = (idx / 200) % 513;
    int b = idx / (200 * 513);
    float val;
    if (n == 0) {
        val = cls[d] + pos[d];
    } else {
        int p = n - 1;
        int t = d >> 3;
        int c = d & 7;
        float raw = conv[b * 102400 + c * 12800 + p * 25 + t];
        int bg = b * 4 + (c >> 1);
        val = gelu_exact((raw - sm[bg]) * sr[bg] * g3[c] + b3[c]);
        int ch = p >> 3, tw = p & 7;
        val += pos[(1 + ch) * 200 + d] + te[tw * 200 + d];
    }
    h[idx] = val;
}

// ---------------- fused weight convert+pad: all four weight sets, one dispatch ----------
__global__ void convpad_all(const float* __restrict__ s0, const float* __restrict__ s1,
                            const float* __restrict__ s2, const float* __restrict__ s3,
                            short* __restrict__ d0, short* __restrict__ d1,
                            short* __restrict__ d2, short* __restrict__ d3) {
    int idx = blockIdx.x * blockDim.x + threadIdx.x;
    const float* src; short* dst; int K, KP, li;
    if (idx < 460800)       { src = s0; dst = d0; K = 200; KP = 256; li = idx; }
    else if (idx < 614400)  { src = s1; dst = d1; K = 200; KP = 256; li = idx - 460800; }
    else if (idx < 1228800) { src = s2; dst = d2; K = 200; KP = 256; li = idx - 614400; }
    else if (idx < 1728000) { src = s3; dst = d3; K = 800; KP = 832; li = idx - 1228800; }
    else return;
    int r = li / (KP >> 2);
    int c4 = (li - r * (KP >> 2)) << 2;
    short4 o;
    if (c4 + 3 < K) {
        float4 f = *(const float4*)&src[(size_t)r * K + c4];
        o.x = f2bf(f.x); o.y = f2bf(f.y); o.z = f2bf(f.z); o.w = f2bf(f.w);
    } else {
        o.x = (c4 + 0 < K) ? f2bf(src[(size_t)r * K + c4 + 0]) : (short)0;
        o.y = (c4 + 1 < K) ? f2bf(src[(size_t)r * K + c4 + 1]) : (short)0;
        o.z = (c4 + 2 < K) ? f2bf(src[(size_t)r * K + c4 + 2]) : (short)0;
        o.w = (c4 + 3 < K) ? f2bf(src[(size_t)r * K + c4 + 3]) : (short)0;
    }
    *(short4*)&dst[(size_t)r * KP + c4] = o;
}

// ---------------- bias precompute: 2 heads per block, float2 table stage ---------------
__global__ __launch_bounds__(256) void bias_lds_kernel(const float* __restrict__ table,
                                                       const int* __restrict__ ridx,
                                                       short* __restrict__ bias) {
    __shared__ float tl0[1908], tl1[1908];
    const int qt = blockIdx.x, hy = blockIdx.y, d = blockIdx.z;
    const int h0 = hy * 2;
    const float* tab = table + d * 19080;
    for (int i = threadIdx.x; i < 1908; i += 256) {
        float2 v = *(const float2*)&tab[i * 10 + h0];   // h0 even -> 8B aligned
        tl0[i] = v.x;
        tl1[i] = v.y;
    }
    __syncthreads();
    const int q0 = qt * 32;
    const int nrows = min(32, 513 - q0);
    short* ob0 = bias + ((size_t)d * 10 + h0) * 513 * 576;
    short* ob1 = ob0 + 513 * 576;
#pragma unroll 2
    for (int lin = threadIdx.x; lin < nrows * 144; lin += 256) {
        int r = lin / 144, j = lin % 144;
        int q = q0 + r;
        const int* rp = ridx + q * 513;
        int k0 = j * 4;
        float a[4], c[4];
#pragma unroll
        for (int e = 0; e < 4; e++) {
            int k = k0 + e;
            if (k < 513) {
                int t = rp[k];
                a[e] = tl0[t];
                c[e] = tl1[t];
            } else {
                a[e] = 0.f;
                c[e] = 0.f;
            }
        }
        uint2 p0, p1;
        p0.x = pack2bf(a[0], a[1]); p0.y = pack2bf(a[2], a[3]);
        p1.x = pack2bf(c[0], c[1]); p1.y = pack2bf(c[2], c[3]);
        *(uint2*)&ob0[(size_t)q * 576 + k0] = p0;
        *(uint2*)&ob1[(size_t)q * 576 + k0] = p1;
    }
}

// ---------------- LayerNorm over D=200; 4 rows per 256-thr block (one wave/row) ----------
__global__ __launch_bounds__(256) void ln_kernel(const float* __restrict__ in,
                                                 const float* __restrict__ g,
                                                 const float* __restrict__ b,
                                                 short* __restrict__ out) {
    int row = blockIdx.x * 4 + (threadIdx.x >> 6);
    int lane = threadIdx.x & 63;
    const float* x = in + (size_t)row * 200;
    float v[4];
    float s = 0.f;
#pragma unroll
    for (int i = 0; i < 4; i++) {
        int d = lane + i * 64;
        v[i] = (d < 200) ? x[d] : 0.f;
        s += v[i];
    }
#pragma unroll
    for (int o = 32; o; o >>= 1) s += __shfl_xor(s, o);
    float mean = s * (1.f / 200.f);
    float s2 = 0.f;
#pragma unroll
    for (int i = 0; i < 4; i++) {
        int d = lane + i * 64;
        float dv = (d < 200) ? (v[i] - mean) : 0.f;
        s2 += dv * dv;
    }
#pragma unroll
    for (int o = 32; o; o >>= 1) s2 += __shfl_xor(s2, o);
    float rstd = rsqrtf(s2 * (1.f / 200.f) + 1e-6f);
#pragma unroll
    for (int i = 0; i < 4; i++) {
        int d = lane + i * 64;
        float val = (d < 200) ? (v[i] - mean) * rstd * g[d] + b[d] : 0.f;
        out[(size_t)row * 256 + d] = f2bf(val);
    }
}

// ---------------- bf16 MFMA GEMM, double-buffered K-loop (BM=32 proven) ----------------
// EPI 1: Cf = res + gamma[n]*(acc+bias[n])
// EPI 2: Cb = bf16(gelu(acc+bias[n])), zero pad cols N..NPout
// EPI 3: qkv scatter -> Qb[b][h][576][32] (scaled), Kb same, Vt[b][h][32][576]
template <int EPI, int BM, int BN>
__global__ __launch_bounds__(256) void gemm_bf(const short* __restrict__ A,
                                               const short* __restrict__ W,
                                               float* __restrict__ Cf,
                                               short* __restrict__ Cb,
                                               const float* __restrict__ res,
                                               const float* __restrict__ bias,
                                               const float* __restrict__ gamma,
                                               int M, int N, int KP, int ldc, int NPout,
                                               short* __restrict__ Qb = nullptr,
                                               short* __restrict__ Kb = nullptr,
                                               short* __restrict__ Vt = nullptr) {
    constexpr int WM = BM / 2, WN = BN / 2;
    constexpr int AM = WM / 16, BNr = WN / 16;
    constexpr int LOADS = (BM + BN) / 32;   // gloads per thread per k-step
    __shared__ __align__(16) short Ss[2][(BM + BN) * 64];

    const int tid = threadIdx.x;
    const int w = tid >> 6, l = tid & 63;
    const int wm = (w >> 1) * WM, wn = (w & 1) * WN;
    const int bm = blockIdx.y * BM, bn = blockIdx.x * BN;

    f32x4 acc[AM][BNr] = {};

    auto stage = [&](int buf, int k0) {
#pragma unroll
        for (int it = 0; it < LOADS; it++) {
            int lin = it * 256 + tid;
            int row = lin >> 3, slot = lin & 7;
            int srcslot = slot ^ (row & 7);
            const short* g;
            if (it * 32 < BM) {
                g = A + (size_t)(bm + row) * KP + k0 + srcslot * 8;
            } else {
                g = W + (size_t)(bn + row - BM) * KP + k0 + srcslot * 8;
            }
            gload_lds16(g, (char*)Ss[buf] + lin * 16);
        }
    };

    const int nk = KP >> 6;
    stage(0, 0);
    int cur = 0;
    for (int kstep = 0; kstep < nk; kstep++) {
        if (kstep + 1 < nk) {
            stage(cur ^ 1, (kstep + 1) << 6);
            if constexpr (LOADS == 6)      asm volatile("s_waitcnt vmcnt(6)" ::: "memory");
            else if constexpr (LOADS == 4) asm volatile("s_waitcnt vmcnt(4)" ::: "memory");
            else                           asm volatile("s_waitcnt vmcnt(3)" ::: "memory");
        } else {
            asm volatile("s_waitcnt vmcnt(0)" ::: "memory");
        }
        __builtin_amdgcn_s_barrier();

        const char* Sc = (const char*)Ss[cur];
#pragma unroll
        for (int kk = 0; kk < 2; kk++) {
            const int kbyte = kk * 64 + (l >> 4) * 16;
            bf16x8 af[AM], bfr[BNr];
#pragma unroll
            for (int i = 0; i < AM; i++) {
                int r = wm + i * 16 + (l & 15);
                af[i] = *(const bf16x8*)(Sc + r * 128 + (kbyte ^ ((r & 7) << 4)));
            }
#pragma unroll
            for (int j = 0; j < BNr; j++) {
                int r = BM + wn + j * 16 + (l & 15);
                bfr[j] = *(const bf16x8*)(Sc + r * 128 + (kbyte ^ ((r & 7) << 4)));
            }
#pragma unroll
            for (int i = 0; i < AM; i++)
#pragma unroll
                for (int j = 0; j < BNr; j++)
                    acc[i][j] = __builtin_amdgcn_mfma_f32_16x16x32_bf16(af[i], bfr[j], acc[i][j], 0, 0, 0);
        }
        __builtin_amdgcn_s_barrier();  // all waves done reading Ss[cur] before overwrite
        cur ^= 1;
    }

    const int col0 = bn + wn + (l & 15);
    const int rbase = (l >> 4) * 4;
#pragma unroll
    for (int i = 0; i < AM; i++) {
#pragma unroll
        for (int r = 0; r < 4; r++) {
            int gm = bm + wm + i * 16 + rbase + r;
            if (gm >= M) continue;
#pragma unroll
            for (int j = 0; j < BNr; j++) {
                int gn = col0 + j * 16;
                float v = acc[i][j][r];
                if (EPI == 1) {
                    if (gn < N) Cf[(size_t)gm * ldc + gn] =
                        res[(size_t)gm * ldc + gn] + gamma[gn] * (v + bias[gn]);
                } else if (EPI == 2) {
                    if (gn < NPout)
                        Cb[(size_t)gm * ldc + gn] = (gn < N) ? f2bf(gelu_exact(v + bias[gn])) : (short)0;
                } else {  // EPI 3: qkv scatter
                    if (gn < 600) {
                        int bb2 = gm / 513, n = gm - bb2 * 513;
                        if (gn < 200) {
                            int hq = gn / 20, dq = gn - hq * 20;
                            Qb[((size_t)(bb2 * 10 + hq) * 576 + n) * 32 + dq] =
                                f2bf(v * 0.22360679774997896f);
                        } else if (gn < 400) {
                            int gk = gn - 200, hk = gk / 20, dk = gk - hk * 20;
                            Kb[((size_t)(bb2 * 10 + hk) * 576 + n) * 32 + dk] = f2bf(v);
                        } else {
                            int gv = gn - 400, hv = gv / 20, dv2 = gv - hv * 20;
                            Vt[((size_t)(bb2 * 10 + hv) * 32 + dv2) * 576 + n] = f2bf(v);
                        }
                    }
                }
            }
        }
    }
}

// ---------------- MFMA flash attention v3: 4-buffer rotation, 1 barrier/tile, -----------
// bias pipelined one tile ahead (r16-proven).
__global__ __launch_bounds__(256) void attn_mfma3(const short* __restrict__ Qb,
                                                  const short* __restrict__ Kb,
                                                  const short* __restrict__ Vt,
                                                  const short* __restrict__ biasb,
                                                  short* __restrict__ ob) {
    __shared__ __align__(16) short Klds[4][64 * 32];
    __shared__ __align__(16) short Vlds[4][32 * 64];
    __shared__ __align__(16) short Pl[4 * 16 * 72];

    const int orig = blockIdx.x;
    const int wg = (orig & 7) * 90 + (orig >> 3);   // XCD-chunked bijection (720 = 8*90)
    const int hh = wg / 72;
    const int rem = wg % 72;
    const int qt = rem >> 3, b = rem & 7;

    const int t = threadIdx.x, wave = t >> 6, l = t & 63;
    const int lq = l & 15, hi = l >> 4;
    const int n = qt * 64 + wave * 16 + lq;
    const int nc = min(n, 512);

    const size_t bh = (size_t)(b * 10 + hh);
    const short* Kbase = Kb + bh * 576 * 32;
    const short* Vbase = Vt + bh * 32 * 576;
    const short* Brow  = biasb + ((size_t)hh * 513 + nc) * 576;

    bf16x8 qf = *(const bf16x8*)&Qb[(bh * 576 + nc) * 32 + hi * 8];

    const int krow = t >> 2, kch = t & 3;
    const short* ksrc = Kbase + (size_t)krow * 32 + (kch ^ ((krow >> 2) & 3)) * 8;
    const int vrow = t >> 3, vch = t & 7;
    const short* vsrc = Vbase + (size_t)vrow * 576 + (vch ^ (vrow & 7)) * 8;

    float mrun = -1e30f, lsum = 0.f;
    f32x4 oacc0 = {}, oacc1 = {};
    const f32x4 zero4 = {};

    uint2 bl_cur[4], bl_next[4];
#pragma unroll
    for (int c = 0; c < 4; c++)
        bl_cur[c] = *(const uint2*)&Brow[c * 16 + hi * 4];
    gload_lds16(ksrc, (char*)Klds[0] + t * 16);
    gload_lds16(vsrc, (char*)Vlds[0] + t * 16);
    gload_lds16(ksrc + 64 * 32, (char*)Klds[1] + t * 16);
    gload_lds16(vsrc + 64, (char*)Vlds[1] + t * 16);

    for (int kt = 0; kt < 9; kt++) {
        const int koff = kt * 64;

        if (kt < 8) {
#pragma unroll
            for (int c = 0; c < 4; c++)
                bl_next[c] = *(const uint2*)&Brow[koff + 64 + c * 16 + hi * 4];
        }
        if (kt < 7) {
            const int knext = koff + 128;
            gload_lds16(ksrc + (size_t)knext * 32, (char*)Klds[(kt + 2) & 3] + t * 16);
            gload_lds16(vsrc + knext, (char*)Vlds[(kt + 2) & 3] + t * 16);
            asm volatile("s_waitcnt vmcnt(8)" ::: "memory");
        } else if (kt == 7) {
            asm volatile("s_waitcnt vmcnt(6)" ::: "memory");
        } else {
            asm volatile("s_waitcnt vmcnt(0)" ::: "memory");
        }
        __builtin_amdgcn_s_barrier();

        const short* Kc = Klds[kt & 3];
        const short* Vc = Vlds[kt & 3];

        f32x4 s[4];
        __builtin_amdgcn_s_setprio(1);
#pragma unroll
        for (int c = 0; c < 4; c++) {
            int r = c * 16 + lq;
            bf16x8 kf = *(const bf16x8*)((const char*)Kc + r * 64 + ((hi ^ ((lq >> 2) & 3)) << 4));
            s[c] = __builtin_amdgcn_mfma_f32_16x16x32_bf16(kf, qf, zero4, 0, 0, 0);
        }
        __builtin_amdgcn_s_setprio(0);

        float sv[4][4];
        float tm = -1e30f;
#pragma unroll
        for (int c = 0; c < 4; c++) {
            float bv[4] = { bf2f((unsigned short)(bl_cur[c].x & 0xFFFF)), bf2f((unsigned short)(bl_cur[c].x >> 16)),
                            bf2f((unsigned short)(bl_cur[c].y & 0xFFFF)), bf2f((unsigned short)(bl_cur[c].y >> 16)) };
            int kglob = koff + c * 16 + hi * 4;
#pragma unroll
            for (int r = 0; r < 4; r++) {
                float val = s[c][r] + bv[r];
                if (kglob + r > 512) val = -1e30f;
                sv[c][r] = val;
                tm = fmaxf(tm, val);
            }
        }
        tm = fmaxf(tm, __shfl_xor(tm, 16));
        tm = fmaxf(tm, __shfl_xor(tm, 32));
        float mnew = fmaxf(mrun, tm);
        float resc = __expf(mrun - mnew);
        mrun = mnew;

        float ts = 0.f;
#pragma unroll
        for (int c = 0; c < 4; c++) {
            float p0 = __expf(sv[c][0] - mnew);
            float p1 = __expf(sv[c][1] - mnew);
            float p2 = __expf(sv[c][2] - mnew);
            float p3 = __expf(sv[c][3] - mnew);
            ts += (p0 + p1) + (p2 + p3);
            uint2 pk;
            pk.x = pack2bf(p0, p1);
            pk.y = pack2bf(p2, p3);
            *(uint2*)&Pl[wave * 1152 + lq * 72 + c * 16 + hi * 4] = pk;
        }
        ts += __shfl_xor(ts, 16);
        ts += __shfl_xor(ts, 32);
        lsum = lsum * resc + ts;
        oacc0 *= resc;
        oacc1 *= resc;

        __builtin_amdgcn_s_setprio(1);
#pragma unroll
        for (int kc = 0; kc < 2; kc++) {
            bf16x8 pf = *(const bf16x8*)&Pl[wave * 1152 + lq * 72 + kc * 32 + hi * 8];
            bf16x8 vf0 = *(const bf16x8*)((const char*)Vc + lq * 128 +
                                          (((kc * 4 + hi) ^ (lq & 7)) << 4));
            bf16x8 vf1 = *(const bf16x8*)((const char*)Vc + (16 + lq) * 128 +
                                          (((kc * 4 + hi) ^ (lq & 7)) << 4));
            oacc0 = __builtin_amdgcn_mfma_f32_16x16x32_bf16(vf0, pf, oacc0, 0, 0, 0);
            oacc1 = __builtin_amdgcn_mfma_f32_16x16x32_bf16(vf1, pf, oacc1, 0, 0, 0);
        }
        __builtin_amdgcn_s_setprio(0);

#pragma unroll
        for (int c = 0; c < 4; c++) bl_cur[c] = bl_next[c];
    }

    if (n < 513) {
        float inv = 1.f / lsum;
        short* op = ob + (size_t)(b * 513 + n) * 256 + hh * 20;
        {
            uint2 pk;
            pk.x = pack2bf(oacc0[0] * inv, oacc0[1] * inv);
            pk.y = pack2bf(oacc0[2] * inv, oacc0[3] * inv);
            *(uint2*)&op[hi * 4] = pk;
        }
        if (hi == 0) {
            uint2 pk;
            pk.x = pack2bf(oacc1[0] * inv, oacc1[1] * inv);
            pk.y = pack2bf(oacc1[2] * inv, oacc1[3] * inv);
            *(uint2*)&op[16] = pk;
        }
    }
}

// ---------------- final: mean-pool patches -> LN -> head (200 -> 4) ----------------
__global__ __launch_bounds__(256) void final_kernel(const float* __restrict__ h,
                                                    const float* __restrict__ g,
                                                    const float* __restrict__ bb,
                                                    const float* __restrict__ hw,
                                                    const float* __restrict__ hb,
                                                    float* __restrict__ out) {
    __shared__ float pool[256];
    __shared__ float red[256];
    int b = blockIdx.x, t = threadIdx.x;
    float s = 0.f;
    if (t < 200) {
        const float* hp = h + b * 513 * 200 + 200 + t;
        for (int p = 0; p < 512; p++) s += hp[p * 200];
        s *= (1.f / 512.f);
    }
    pool[t] = (t < 200) ? s : 0.f;
    red[t] = pool[t];
    __syncthreads();
    for (int o = 128; o; o >>= 1) {
        if (t < o) red[t] += red[t + o];
        __syncthreads();
    }
    float mean = red[0] / 200.f;
    __syncthreads();
    float dv = (t < 200) ? (pool[t] - mean) : 0.f;
    red[t] = dv * dv;
    __syncthreads();
    for (int o = 128; o; o >>= 1) {
        if (t < o) red[t] += red[t + o];
        __syncthreads();
    }
    float var = red[0] / 200.f;
    float rstd = rsqrtf(var + 1e-6f);
    __syncthreads();
    if (t < 200) pool[t] = (pool[t] - mean) * rstd * g[t] + bb[t];
    __syncthreads();
    if (t < 4) {
        float acc = hb[t];
        for (int d2 = 0; d2 < 200; d2++) acc += pool[d2] * hw[t * 200 + d2];
        out[b * 4 + t] = acc;
    }
}

extern "C" void kernel_launch(void* const* d_in, const int* in_sizes, int n_in,
                              void* d_out, int out_size, void* d_ws, size_t ws_size,
                              hipStream_t stream) {
    const float* x        = (const float*)d_in[0];
    const float* conv1_w  = (const float*)d_in[1];
    const float* conv1_b  = (const float*)d_in[2];
    const float* gn1_g    = (const float*)d_in[3];
    const float* gn1_b    = (const float*)d_in[4];
    const float* conv2_w  = (const float*)d_in[5];
    const float* conv2_b  = (const float*)d_in[6];
    const float* gn2_g    = (const float*)d_in[7];
    const float* gn2_b    = (const float*)d_in[8];
    const float* conv3_w  = (const float*)d_in[9];
    const float* conv3_b  = (const float*)d_in[10];
    const float* gn3_g    = (const float*)d_in[11];
    const float* gn3_b    = (const float*)d_in[12];
    const float* cls_tok  = (const float*)d_in[13];
    const float* pos_emb  = (const float*)d_in[14];
    const float* time_emb = (const float*)d_in[15];
    const float* ln1_g    = (const float*)d_in[16];
    const float* ln1_b    = (const float*)d_in[17];
    const float* qkv_w    = (const float*)d_in[18];
    const float* rel_tab  = (const float*)d_in[19];
    const float* proj_w   = (const float*)d_in[20];
    const float* proj_b   = (const float*)d_in[21];
    const float* gamma1   = (const float*)d_in[22];
    const float* ln2_g    = (const float*)d_in[23];
    const float* ln2_b    = (const float*)d_in[24];
    const float* fc1_w    = (const float*)d_in[25];
    const float* fc1_b    = (const float*)d_in[26];
    const float* fc2_w    = (const float*)d_in[27];
    const float* fc2_b    = (const float*)d_in[28];
    const float* gamma2   = (const float*)d_in[29];
    const float* fcn_g    = (const float*)d_in[30];
    const float* fcn_b    = (const float*)d_in[31];
    const float* head_w   = (const float*)d_in[32];
    const float* head_b   = (const float*)d_in[33];
    const int*   rel_idx  = (const int*)d_in[34];

    // ---- workspace layout (bytes), total ~102 MB ----
    char* p = (char*)d_ws;
    float* h    = (float*)p; p += 3283200;          // 8*513*200 f32
    char* qreg = p;                                  // multi-phase region
    float* c1   = (float*)qreg;
    float* c2   = c1 + 819200;
    short* Qb   = (short*)qreg;                     // [8][10][576][32]
    short* Kb   = Qb + 1474560;
    short* Vt   = Kb + 1474560;                     // [8][10][32][576]
    short* mlp  = (short*)qreg;                     // [4104][832] (MLP phase)
    p += 9849600;
    short* y    = (short*)p; p += 2101248;          // 4104*256 bf16
    short* ob   = (short*)p; p += 2101248;          // 4104*256 bf16
    short* wqkv = (short*)p; p += 3686400;
    short* wproj= (short*)p; p += 1228800;
    short* wfc1 = (short*)p; p += 4915200;
    short* wfc2 = (short*)p; p += 3993600;
    short* biasb= (short*)p; p += 12 * 5909760;     // [12][10][513][576] bf16 = 70.9 MB
    float* part = (float*)p;                        // 512*2 f32 partials

    // ---- upfront precompute ----
    convpad_all<<<6750, 256, 0, stream>>>(qkv_w, proj_w, fc1_w, fc2_w, wqkv, wproj, wfc1, wfc2);
    bias_lds_kernel<<<dim3(17, 5, 12), 256, 0, stream>>>(rel_tab, rel_idx, biasb);
    hipMemsetAsync(ob, 0, 2101248, stream);

    // ---- patch embed ----
    conv1_kernel<<<3200, 256, 0, stream>>>(x, conv1_w, conv1_b, c1);
    gn_stats1<<<512, 256, 0, stream>>>(c1, part);
    gn_apply_kernel<<<3200, 256, 0, stream>>>(c1, part, gn1_g, gn1_b);
    conv3x1_kernel<<<3200, 256, 0, stream>>>(c1, conv2_w, conv2_b, c2);
    gn_stats1<<<512, 256, 0, stream>>>(c2, part);
    gn_apply_kernel<<<3200, 256, 0, stream>>>(c2, part, gn2_g, gn2_b);
    conv3x1_kernel<<<3200, 256, 0, stream>>>(c2, conv3_w, conv3_b, c1);
    gn_stats1<<<512, 256, 0, stream>>>(c1, part);
    embed_kernel<<<(820800 + 255) / 256, 256, 0, stream>>>(c1, part, gn3_g, gn3_b,
                                                           cls_tok, pos_emb, time_emb, h);

    hipMemsetAsync(Qb, 0, 3 * 1474560 * 2, stream);  // zero QKV pad regions (post conv phase)

    // ---- transformer layers ----
    for (int d = 0; d < 12; d++) {
        ln_kernel<<<1026, 256, 0, stream>>>(h, ln1_g + d * 200, ln1_b + d * 200, y);
        gemm_bf<3, 32, 64><<<dim3(10, 129), 256, 0, stream>>>(y, wqkv + d * 153600,
                                                              nullptr, nullptr, nullptr, nullptr, nullptr,
                                                              4104, 600, 256, 0, 0, Qb, Kb, Vt);
        attn_mfma3<<<720, 256, 0, stream>>>(Qb, Kb, Vt, biasb + (size_t)d * 2954880, ob);
        gemm_bf<1, 32, 64><<<dim3(4, 129), 256, 0, stream>>>(ob, wproj + d * 51200, h, nullptr,
                                                             h, proj_b + d * 200, gamma1 + d * 200,
                                                             4104, 200, 256, 200, 0);
        ln_kernel<<<1026, 256, 0, stream>>>(h, ln2_g + d * 200, ln2_b + d * 200, y);
        gemm_bf<2, 32, 64><<<dim3(13, 129), 256, 0, stream>>>(y, wfc1 + d * 204800, nullptr, mlp,
                                                              nullptr, fc1_b + d * 800, nullptr,
                                                              4104, 800, 256, 832, 832);
        gemm_bf<1, 32, 64><<<dim3(4, 129), 256, 0, stream>>>(mlp, wfc2 + d * 166400, h, nullptr,
                                                             h, fc2_b + d * 200, gamma2 + d * 200,
                                                             4104, 200, 832, 200, 0);
    }

    // ---- pool + head ----
    final_kernel<<<8, 256, 0, stream>>>(h, fcn_g, fcn_b, head_w, head_b, (float*)d_out);
}